// Round 1
// baseline (1801.955 us; speedup 1.0000x reference)
//
#include <hip/hip_runtime.h>
#include <hip/hip_bf16.h>

#define DI __device__ __forceinline__

typedef __attribute__((ext_vector_type(8))) __bf16 bf16x8;
typedef __attribute__((ext_vector_type(8))) short short8;
typedef __attribute__((ext_vector_type(4))) float f32x4;

DI short f2b(float f) {
    union { float f; unsigned u; } v; v.f = f;
    unsigned r = v.u + 0x7FFFu + ((v.u >> 16) & 1u);
    return (short)(r >> 16);
}
DI float b2f(short s) {
    union { unsigned u; float f; } v; v.u = ((unsigned)(unsigned short)s) << 16;
    return v.f;
}

// ---------------------------------------------------------------------------
// Generic 64x64 MFMA bf16 GEMM: C[M][N] = A[M][K] @ Wt[N][K]^T (+bias) (+resid)
// A, Wt bf16 (as short). OB: bf16 out else f32. HB: bias. HR: residual (f32).
// Requires K % 32 == 0; A/Wt buffers must be readable up to tile-rounded rows.
// ---------------------------------------------------------------------------
template<int OB, int HB, int HR>
__global__ __launch_bounds__(256)
void gemm64(const short* __restrict__ A, int lda, long long sA,
            const short* __restrict__ Wt, int ldw, long long sW,
            const float* __restrict__ bias,
            void* __restrict__ Cv, int ldc, long long sC,
            const float* __restrict__ R, int ldr, long long sR,
            int M, int N, int K)
{
    __shared__ short As[2048];
    __shared__ short Bs[2048];
    const int z = blockIdx.z;
    A  += (long long)z * sA;
    Wt += (long long)z * sW;
    const int m0 = blockIdx.y * 64, n0 = blockIdx.x * 64;
    const int tid = threadIdx.x, lane = tid & 63, wv = tid >> 6;
    const int wr = wv >> 1, wc = wv & 1;
    const int lrow = tid >> 2, lch = tid & 3;
    const int wch = lch ^ (lrow & 3);

    f32x4 zero = {0.f, 0.f, 0.f, 0.f};
    f32x4 acc00 = zero, acc01 = zero, acc10 = zero, acc11 = zero;

    const short* arow = &A[(long long)(m0 + lrow) * lda + lch * 8];
    const short* brow = &Wt[(long long)(n0 + lrow) * ldw + lch * 8];
    short* asw = &As[lrow * 32 + wch * 8];
    short* bsw = &Bs[lrow * 32 + wch * 8];

    const int fr = lane & 15, fg = lane >> 4;
    const int c = ((fg ^ (fr & 3)) * 8);
    const int a0off = (wr * 32 + fr) * 32 + c;
    const int b0off = (wc * 32 + fr) * 32 + c;

    for (int k0 = 0; k0 < K; k0 += 32) {
        uint4 av = *(const uint4*)arow; arow += 32;
        uint4 bv = *(const uint4*)brow; brow += 32;
        __syncthreads();
        *(uint4*)asw = av;
        *(uint4*)bsw = bv;
        __syncthreads();
        bf16x8 a0 = *(const bf16x8*)&As[a0off];
        bf16x8 a1 = *(const bf16x8*)&As[a0off + 512];
        bf16x8 b0 = *(const bf16x8*)&Bs[b0off];
        bf16x8 b1 = *(const bf16x8*)&Bs[b0off + 512];
        acc00 = __builtin_amdgcn_mfma_f32_16x16x32_bf16(a0, b0, acc00, 0, 0, 0);
        acc01 = __builtin_amdgcn_mfma_f32_16x16x32_bf16(a0, b1, acc01, 0, 0, 0);
        acc10 = __builtin_amdgcn_mfma_f32_16x16x32_bf16(a1, b0, acc10, 0, 0, 0);
        acc11 = __builtin_amdgcn_mfma_f32_16x16x32_bf16(a1, b1, acc11, 0, 0, 0);
    }

    const long long cz = (long long)z * sC;
    const int rbase = m0 + wr * 32 + fg * 4;
    const int cbase = n0 + wc * 32 + fr;
    auto emit = [&](f32x4 a, int mi, int ni) {
        int cc = cbase + ni * 16;
        if (cc >= N) return;
        float bv = HB ? bias[cc] : 0.f;
        #pragma unroll
        for (int v = 0; v < 4; v++) {
            int rr = rbase + mi * 16 + v;
            if (rr >= M) continue;
            float val = a[v] + bv;
            if (HR) val += R[(long long)z * sR + (long long)rr * ldr + cc];
            if (OB) ((short*)Cv)[cz + (long long)rr * ldc + cc] = f2b(val);
            else    ((float*)Cv)[cz + (long long)rr * ldc + cc] = val;
        }
    };
    emit(acc00, 0, 0); emit(acc01, 0, 1); emit(acc10, 1, 0); emit(acc11, 1, 1);
}

// ---------------------------------------------------------------------------
// LayerNorm over C=128: f32 in -> bf16 out. One wave per row.
// ---------------------------------------------------------------------------
__global__ __launch_bounds__(256)
void ln_kernel(const float* __restrict__ x, const float* __restrict__ g,
               const float* __restrict__ b, short* __restrict__ o, int rows)
{
    int row = blockIdx.x * 4 + (threadIdx.x >> 6);
    if (row >= rows) return;
    int lane = threadIdx.x & 63;
    const float2 v = *(const float2*)&x[(long long)row * 128 + lane * 2];
    float s = v.x + v.y;
    float ss = v.x * v.x + v.y * v.y;
    #pragma unroll
    for (int off = 1; off < 64; off <<= 1) {
        s += __shfl_xor(s, off);
        ss += __shfl_xor(ss, off);
    }
    float mu = s * 0.0078125f;
    float var = ss * 0.0078125f - mu * mu;
    float rs = rsqrtf(var + 1e-5f);
    float2 gg = *(const float2*)&g[lane * 2];
    float2 bb = *(const float2*)&b[lane * 2];
    short2 out;
    out.x = f2b((v.x - mu) * rs * gg.x + bb.x);
    out.y = f2b((v.y - mu) * rs * gg.y + bb.y);
    *(short2*)&o[(long long)row * 128 + lane * 2] = out;
}

// f32 [K][N] -> bf16 [N][K]
__global__ void wtrans(const float* __restrict__ w, short* __restrict__ wt, int K, int N)
{
    long long idx = (long long)blockIdx.x * 256 + threadIdx.x;
    if (idx >= (long long)K * N) return;
    int k = (int)(idx / N), n = (int)(idx % N);
    wt[(long long)n * K + k] = f2b(w[idx]);
}

// ---------------------------------------------------------------------------
// Local windowed attention: one block per 7x7 window, all 4 heads.
// qkv: per-batch [12544][384] bf16. att: per-batch [12544][128] bf16.
// ---------------------------------------------------------------------------
__global__ __launch_bounds__(256)
void lattn(const short* __restrict__ qkv, short* __restrict__ att)
{
    __shared__ float sm[49 * 33 * 3 + 49 * 50];
    float* qs = sm;
    float* ks = sm + 1617;
    float* vs = sm + 3234;
    float* S  = sm + 4851;
    const int wy = blockIdx.x >> 4, wx = blockIdx.x & 15;
    const int tid = threadIdx.x;
    const int lane = tid & 63, wvi = tid >> 6;

    for (int h = 0; h < 4; h++) {
        // stage q,k,v for this head into LDS (f32)
        for (int idx = tid; idx < 588; idx += 256) {
            int arr = idx / 196, rem = idx % 196;
            int i = rem >> 2, dg = rem & 3;
            int n = (wy * 7 + i / 7) * 112 + wx * 7 + i % 7;
            short8 v = *(const short8*)&qkv[(long long)n * 384 + arr * 128 + h * 32 + dg * 8];
            float* dst = (arr == 0) ? qs : (arr == 1) ? ks : vs;
            #pragma unroll
            for (int u = 0; u < 8; u++) dst[i * 33 + dg * 8 + u] = b2f(v[u]);
        }
        __syncthreads();
        // scores S[i][j] = (q_i . k_j) * scale, j blocked by 8
        for (int idx = tid; idx < 343; idx += 256) {
            int i = idx / 7, jg = idx % 7;
            int j0 = jg * 8, jn = (jg == 6) ? 1 : 8;
            float s[8] = {0, 0, 0, 0, 0, 0, 0, 0};
            for (int d = 0; d < 32; d++) {
                float qv = qs[i * 33 + d];
                #pragma unroll
                for (int u = 0; u < 8; u++) s[u] += qv * ks[(j0 + u) * 33 + d];
            }
            for (int u = 0; u < jn; u++) S[i * 50 + j0 + u] = s[u] * 0.17677669529663689f;
        }
        __syncthreads();
        // softmax rows (wave per row)
        for (int r = wvi; r < 49; r += 4) {
            float v = (lane < 49) ? S[r * 50 + lane] : -1e30f;
            float mx = v;
            #pragma unroll
            for (int off = 1; off < 64; off <<= 1) mx = fmaxf(mx, __shfl_xor(mx, off));
            float e = (lane < 49) ? __expf(v - mx) : 0.f;
            float sum = e;
            #pragma unroll
            for (int off = 1; off < 64; off <<= 1) sum += __shfl_xor(sum, off);
            if (lane < 49) S[r * 50 + lane] = e / sum;
        }
        __syncthreads();
        // O = P @ V, d blocked by 8
        for (int idx = tid; idx < 196; idx += 256) {
            int i = idx >> 2, dg = idx & 3, d0 = dg * 8;
            float o[8] = {0, 0, 0, 0, 0, 0, 0, 0};
            for (int j = 0; j < 49; j++) {
                float p = S[i * 50 + j];
                #pragma unroll
                for (int u = 0; u < 8; u++) o[u] += p * vs[j * 33 + d0 + u];
            }
            int n = (wy * 7 + i / 7) * 112 + wx * 7 + i % 7;
            short8 ov;
            #pragma unroll
            for (int u = 0; u < 8; u++) ov[u] = f2b(o[u]);
            *(short8*)&att[(long long)n * 128 + h * 32 + d0] = ov;
        }
        __syncthreads();
    }
}

// ---------------------------------------------------------------------------
// Depthwise 3x3 conv (SAME) + bias + exact GELU on [112*112][512] bf16 (per b)
// ---------------------------------------------------------------------------
__global__ __launch_bounds__(256)
void dwgelu(const short* __restrict__ h1, const float* __restrict__ w,
            const float* __restrict__ bias, short* __restrict__ h2)
{
    int idx = blockIdx.x * 256 + threadIdx.x;
    int cb = idx & 63, pix = idx >> 6;
    int x = pix % 112, y = pix / 112;
    int c0 = cb << 3;
    float acc[8];
    #pragma unroll
    for (int u = 0; u < 8; u++) acc[u] = bias[c0 + u];
    for (int ky = 0; ky < 3; ky++) {
        int yy = y + ky - 1;
        if (yy < 0 || yy >= 112) continue;
        for (int kx = 0; kx < 3; kx++) {
            int xx = x + kx - 1;
            if (xx < 0 || xx >= 112) continue;
            short8 v = *(const short8*)&h1[((long long)(yy * 112 + xx)) * 512 + c0];
            const float* wp = &w[(ky * 3 + kx) * 512 + c0];
            #pragma unroll
            for (int u = 0; u < 8; u++) acc[u] += b2f(v[u]) * wp[u];
        }
    }
    short8 ov;
    #pragma unroll
    for (int u = 0; u < 8; u++) {
        float a = acc[u];
        ov[u] = f2b(0.5f * a * (1.f + erff(a * 0.7071067811865475f)));
    }
    *(short8*)&h2[(long long)pix * 512 + c0] = ov;
}

// gather 8x8 patches: LNF [B*12544][128] bf16 -> PATCH [1568(pad1600)][8192] bf16
__global__ void patchk(const short* __restrict__ lnf, short* __restrict__ patch)
{
    int idx = blockIdx.x * 256 + threadIdx.x;
    if (idx >= 1568 * 1024) return;
    int row = idx >> 10, ch = idx & 1023;
    int kh = ch >> 7, kw = (ch >> 4) & 7, ic8 = ch & 15;
    int b = row / 196, p = row % 196;
    int oh = p / 14, ow = p % 14;
    int y = oh * 8 + kh, x = ow * 8 + kw;
    short8 v = *(const short8*)&lnf[(((long long)b * 12544) + y * 112 + x) * 128 + ic8 * 8];
    *(short8*)&patch[(long long)row * 8192 + ch * 8] = v;
}

// pack k,v: KVB [1568][256] -> KPACK [32][256][32] (rows>=196 stay 0),
//                              VTPACK [32][64][224] (cols>=196 stay 0)
__global__ void packkv(const short* __restrict__ kvb, short* __restrict__ kp,
                       short* __restrict__ vt)
{
    int idx = blockIdx.x * 256 + threadIdx.x;
    if (idx >= 32 * 196 * 32) return;
    int d = idx & 31;
    int m = (idx >> 5) % 196;
    int bh = idx / (196 * 32);
    int b = bh >> 2, h = bh & 3;
    long long src = ((long long)b * 196 + m) * 256 + h * 32 + d;
    kp[((long long)bh * 256 + m) * 32 + d] = kvb[src];
    vt[((long long)bh * 64 + d) * 224 + m] = kvb[src + 128];
}

// softmax rows of S (per b): [4*12544][224], 196 valid cols, scale folded in
__global__ __launch_bounds__(256)
void smax(short* __restrict__ S)
{
    const float SC = 0.17677669529663689f;
    int row = blockIdx.x * 4 + (threadIdx.x >> 6);
    int lane = threadIdx.x & 63;
    short* p = S + (long long)row * 224;
    float v0 = b2f(p[lane]) * SC;
    float v1 = b2f(p[lane + 64]) * SC;
    float v2 = b2f(p[lane + 128]) * SC;
    float v3 = (lane < 4) ? b2f(p[lane + 192]) * SC : -1e30f;
    float mx = fmaxf(fmaxf(v0, v1), fmaxf(v2, v3));
    #pragma unroll
    for (int off = 1; off < 64; off <<= 1) mx = fmaxf(mx, __shfl_xor(mx, off));
    float e0 = __expf(v0 - mx), e1 = __expf(v1 - mx), e2 = __expf(v2 - mx);
    float e3 = (lane < 4) ? __expf(v3 - mx) : 0.f;
    float s = e0 + e1 + e2 + e3;
    #pragma unroll
    for (int off = 1; off < 64; off <<= 1) s += __shfl_xor(s, off);
    float inv = 1.f / s;
    p[lane] = f2b(e0 * inv);
    p[lane + 64] = f2b(e1 * inv);
    p[lane + 128] = f2b(e2 * inv);
    if (lane < 4) p[lane + 192] = f2b(e3 * inv);
}

// ---------------------------------------------------------------------------
extern "C" void kernel_launch(void* const* d_in, const int* in_sizes, int n_in,
                              void* d_out, int out_size, void* d_ws, size_t ws_size,
                              hipStream_t stream)
{
    (void)in_sizes; (void)n_in; (void)out_size; (void)ws_size;
    const float* X      = (const float*)d_in[0];
    const float* l_n1_g = (const float*)d_in[1];
    const float* l_n1_b = (const float*)d_in[2];
    const float* l_qkv_w= (const float*)d_in[3];
    const float* l_qkv_b= (const float*)d_in[4];
    const float* l_pw   = (const float*)d_in[5];
    const float* l_pb   = (const float*)d_in[6];
    const float* l_n2_g = (const float*)d_in[7];
    const float* l_n2_b = (const float*)d_in[8];
    const float* l_f1w  = (const float*)d_in[9];
    const float* l_f1b  = (const float*)d_in[10];
    const float* l_dww  = (const float*)d_in[11];
    const float* l_dwb  = (const float*)d_in[12];
    const float* l_f2w  = (const float*)d_in[13];
    const float* l_f2b  = (const float*)d_in[14];
    const float* g_n1_g = (const float*)d_in[15];
    const float* g_n1_b = (const float*)d_in[16];
    const float* g_qw   = (const float*)d_in[17];
    const float* g_qb   = (const float*)d_in[18];
    const float* g_kvw  = (const float*)d_in[19];
    const float* g_kvb  = (const float*)d_in[20];
    const float* g_srw  = (const float*)d_in[21];
    const float* g_srb  = (const float*)d_in[22];
    const float* g_sng  = (const float*)d_in[23];
    const float* g_snb  = (const float*)d_in[24];
    const float* g_pw   = (const float*)d_in[25];
    const float* g_pb   = (const float*)d_in[26];
    const float* g_n2_g = (const float*)d_in[27];
    const float* g_n2_b = (const float*)d_in[28];
    const float* g_f1w  = (const float*)d_in[29];
    const float* g_f1b  = (const float*)d_in[30];
    const float* g_dww  = (const float*)d_in[31];
    const float* g_dwb  = (const float*)d_in[32];
    const float* g_f2w  = (const float*)d_in[33];
    const float* g_f2b  = (const float*)d_in[34];

    const long long NPB = 12544;   // tokens per batch image
    const long long BN  = 100352;  // total tokens

    float* OUT = (float*)d_out;
    char* ws = (char*)d_ws;
    size_t off = 0;
    auto alloc = [&](size_t bytes) { size_t o = off; off += (bytes + 255) & ~(size_t)255; return o; };
    short* WT_QKV = (short*)(ws + alloc(384 * 128 * 2));
    short* WT_LPW = (short*)(ws + alloc(128 * 128 * 2));
    short* WT_LF1 = (short*)(ws + alloc(512 * 128 * 2));
    short* WT_LF2 = (short*)(ws + alloc(128 * 512 * 2));
    short* WT_GQ  = (short*)(ws + alloc(128 * 128 * 2));
    short* WT_GKV = (short*)(ws + alloc(256 * 128 * 2));
    short* WT_GSR = (short*)(ws + alloc(128 * 8192 * 2));
    short* WT_GPW = (short*)(ws + alloc(128 * 128 * 2));
    short* WT_GF1 = (short*)(ws + alloc(512 * 128 * 2));
    short* WT_GF2 = (short*)(ws + alloc(128 * 512 * 2));
    short* LNF    = (short*)(ws + alloc((size_t)BN * 128 * 2));
    short* QKVB   = (short*)(ws + alloc((size_t)NPB * 384 * 2));
    short* ATT    = (short*)(ws + alloc((size_t)BN * 128 * 2));
    short* H1     = (short*)(ws + alloc((size_t)NPB * 512 * 2));
    short* H2     = (short*)(ws + alloc((size_t)NPB * 512 * 2));
    short* QBUF   = (short*)(ws + alloc((size_t)BN * 128 * 2));
    short* PATCH  = (short*)(ws + alloc((size_t)1600 * 8192 * 2));
    float* XS     = (float*)(ws + alloc((size_t)1600 * 128 * 4));
    short* XSLN   = (short*)(ws + alloc((size_t)1600 * 128 * 2));
    short* KVB    = (short*)(ws + alloc((size_t)1600 * 256 * 2));
    short* KPACK  = (short*)(ws + alloc((size_t)32 * 256 * 32 * 2));
    short* VTPACK = (short*)(ws + alloc((size_t)32 * 64 * 224 * 2));
    short* SB     = (short*)(ws + alloc((size_t)4 * NPB * 224 * 2));

    // residual stream starts as x (f32, in d_out)
    hipMemcpyAsync(OUT, X, (size_t)BN * 128 * 4, hipMemcpyDeviceToDevice, stream);

    // weight transposes -> bf16 [N][K]
    wtrans<<<192, 256, 0, stream>>>(l_qkv_w, WT_QKV, 128, 384);
    wtrans<<<64, 256, 0, stream>>>(l_pw, WT_LPW, 128, 128);
    wtrans<<<256, 256, 0, stream>>>(l_f1w, WT_LF1, 128, 512);
    wtrans<<<256, 256, 0, stream>>>(l_f2w, WT_LF2, 512, 128);
    wtrans<<<64, 256, 0, stream>>>(g_qw, WT_GQ, 128, 128);
    wtrans<<<128, 256, 0, stream>>>(g_kvw, WT_GKV, 128, 256);
    wtrans<<<4096, 256, 0, stream>>>(g_srw, WT_GSR, 8192, 128);
    wtrans<<<64, 256, 0, stream>>>(g_pw, WT_GPW, 128, 128);
    wtrans<<<256, 256, 0, stream>>>(g_f1w, WT_GF1, 128, 512);
    wtrans<<<256, 256, 0, stream>>>(g_f2w, WT_GF2, 512, 128);

    // ---------------- Local attention block ----------------
    ln_kernel<<<25088, 256, 0, stream>>>(OUT, l_n1_g, l_n1_b, LNF, (int)BN);
    for (int b = 0; b < 8; b++) {
        gemm64<1, 1, 0><<<dim3(6, 196, 1), 256, 0, stream>>>(
            LNF + (long long)b * NPB * 128, 128, 0, WT_QKV, 128, 0, l_qkv_b,
            QKVB, 384, 0, nullptr, 0, 0, 12544, 384, 128);
        lattn<<<256, 256, 0, stream>>>(QKVB, ATT + (long long)b * NPB * 128);
    }
    gemm64<0, 1, 1><<<dim3(2, 1568, 1), 256, 0, stream>>>(
        ATT, 128, 0, WT_LPW, 128, 0, l_pb,
        OUT, 128, 0, OUT, 128, 0, (int)BN, 128, 128);

    // ---------------- Local MLP block ----------------
    ln_kernel<<<25088, 256, 0, stream>>>(OUT, l_n2_g, l_n2_b, LNF, (int)BN);
    for (int b = 0; b < 8; b++) {
        gemm64<1, 1, 0><<<dim3(8, 196, 1), 256, 0, stream>>>(
            LNF + (long long)b * NPB * 128, 128, 0, WT_LF1, 128, 0, l_f1b,
            H1, 512, 0, nullptr, 0, 0, 12544, 512, 128);
        dwgelu<<<3136, 256, 0, stream>>>(H1, l_dww, l_dwb, H2);
        gemm64<0, 1, 1><<<dim3(2, 196, 1), 256, 0, stream>>>(
            H2, 512, 0, WT_LF2, 512, 0, l_f2b,
            OUT + (long long)b * NPB * 128, 128, 0,
            OUT + (long long)b * NPB * 128, 128, 0, 12544, 128, 512);
    }

    // ---------------- Global attention block ----------------
    ln_kernel<<<25088, 256, 0, stream>>>(OUT, g_n1_g, g_n1_b, LNF, (int)BN);
    gemm64<1, 1, 0><<<dim3(2, 1568, 1), 256, 0, stream>>>(
        LNF, 128, 0, WT_GQ, 128, 0, g_qb,
        QBUF, 128, 0, nullptr, 0, 0, (int)BN, 128, 128);
    patchk<<<6272, 256, 0, stream>>>(LNF, PATCH);
    gemm64<0, 1, 0><<<dim3(2, 25, 1), 256, 0, stream>>>(
        PATCH, 8192, 0, WT_GSR, 8192, 0, g_srb,
        XS, 128, 0, nullptr, 0, 0, 1568, 128, 8192);
    ln_kernel<<<392, 256, 0, stream>>>(XS, g_sng, g_snb, XSLN, 1568);
    gemm64<1, 1, 0><<<dim3(4, 25, 1), 256, 0, stream>>>(
        XSLN, 128, 0, WT_GKV, 128, 0, g_kvb,
        KVB, 256, 0, nullptr, 0, 0, 1568, 256, 128);
    hipMemsetAsync(KPACK, 0, (size_t)32 * 256 * 32 * 2, stream);
    hipMemsetAsync(VTPACK, 0, (size_t)32 * 64 * 224 * 2, stream);
    packkv<<<784, 256, 0, stream>>>(KVB, KPACK, VTPACK);
    for (int b = 0; b < 8; b++) {
        gemm64<1, 0, 0><<<dim3(4, 196, 4), 256, 0, stream>>>(
            QBUF + (long long)b * NPB * 128, 128, 32,
            KPACK + (long long)b * 4 * 256 * 32, 32, 256 * 32, nullptr,
            SB, 224, (long long)12544 * 224, nullptr, 0, 0, 12544, 224, 32);
        smax<<<12544, 256, 0, stream>>>(SB);
        gemm64<1, 0, 0><<<dim3(1, 196, 4), 256, 0, stream>>>(
            SB, 224, (long long)12544 * 224,
            VTPACK + (long long)b * 4 * 64 * 224, 224, 64 * 224, nullptr,
            ATT + (long long)b * NPB * 128, 128, 32, nullptr, 0, 0, 12544, 32, 224);
    }
    gemm64<0, 1, 1><<<dim3(2, 1568, 1), 256, 0, stream>>>(
        ATT, 128, 0, WT_GPW, 128, 0, g_pb,
        OUT, 128, 0, OUT, 128, 0, (int)BN, 128, 128);

    // ---------------- Global MLP block ----------------
    ln_kernel<<<25088, 256, 0, stream>>>(OUT, g_n2_g, g_n2_b, LNF, (int)BN);
    for (int b = 0; b < 8; b++) {
        gemm64<1, 1, 0><<<dim3(8, 196, 1), 256, 0, stream>>>(
            LNF + (long long)b * NPB * 128, 128, 0, WT_GF1, 128, 0, g_f1b,
            H1, 512, 0, nullptr, 0, 0, 12544, 512, 128);
        dwgelu<<<3136, 256, 0, stream>>>(H1, g_dww, g_dwb, H2);
        gemm64<0, 1, 1><<<dim3(2, 196, 1), 256, 0, stream>>>(
            H2, 512, 0, WT_GF2, 512, 0, g_f2b,
            OUT + (long long)b * NPB * 128, 128, 0,
            OUT + (long long)b * NPB * 128, 128, 0, 12544, 128, 512);
    }
}

// Round 2
// 1062.272 us; speedup vs baseline: 1.6963x; 1.6963x over previous
//
#include <hip/hip_runtime.h>
#include <hip/hip_bf16.h>

#define DI __device__ __forceinline__

typedef __attribute__((ext_vector_type(8))) __bf16 bf16x8;
typedef __attribute__((ext_vector_type(8))) short short8;
typedef __attribute__((ext_vector_type(4))) float f32x4;

DI short f2b(float f) {
    union { float f; unsigned u; } v; v.f = f;
    unsigned r = v.u + 0x7FFFu + ((v.u >> 16) & 1u);
    return (short)(r >> 16);
}
DI float b2f(short s) {
    union { unsigned u; float f; } v; v.u = ((unsigned)(unsigned short)s) << 16;
    return v.f;
}

// ---------------------------------------------------------------------------
// Generic 64x64 MFMA bf16 GEMM: C[M][N] = A[M][K] @ Wt[N][K]^T (+bias) (+resid)
// ---------------------------------------------------------------------------
template<int OB, int HB, int HR>
__global__ __launch_bounds__(256)
void gemm64(const short* __restrict__ A, int lda, long long sA,
            const short* __restrict__ Wt, int ldw, long long sW,
            const float* __restrict__ bias,
            void* __restrict__ Cv, int ldc, long long sC,
            const float* __restrict__ R, int ldr, long long sR,
            int M, int N, int K)
{
    __shared__ short As[2048];
    __shared__ short Bs[2048];
    const int z = blockIdx.z;
    A  += (long long)z * sA;
    Wt += (long long)z * sW;
    const int m0 = blockIdx.y * 64, n0 = blockIdx.x * 64;
    const int tid = threadIdx.x, lane = tid & 63, wv = tid >> 6;
    const int wr = wv >> 1, wc = wv & 1;
    const int lrow = tid >> 2, lch = tid & 3;
    const int wch = lch ^ (lrow & 3);

    f32x4 zero = {0.f, 0.f, 0.f, 0.f};
    f32x4 acc00 = zero, acc01 = zero, acc10 = zero, acc11 = zero;

    const short* arow = &A[(long long)(m0 + lrow) * lda + lch * 8];
    const short* brow = &Wt[(long long)(n0 + lrow) * ldw + lch * 8];
    short* asw = &As[lrow * 32 + wch * 8];
    short* bsw = &Bs[lrow * 32 + wch * 8];

    const int fr = lane & 15, fg = lane >> 4;
    const int c = ((fg ^ (fr & 3)) * 8);
    const int a0off = (wr * 32 + fr) * 32 + c;
    const int b0off = (wc * 32 + fr) * 32 + c;

    for (int k0 = 0; k0 < K; k0 += 32) {
        uint4 av = *(const uint4*)arow; arow += 32;
        uint4 bv = *(const uint4*)brow; brow += 32;
        __syncthreads();
        *(uint4*)asw = av;
        *(uint4*)bsw = bv;
        __syncthreads();
        bf16x8 a0 = *(const bf16x8*)&As[a0off];
        bf16x8 a1 = *(const bf16x8*)&As[a0off + 512];
        bf16x8 b0 = *(const bf16x8*)&Bs[b0off];
        bf16x8 b1 = *(const bf16x8*)&Bs[b0off + 512];
        acc00 = __builtin_amdgcn_mfma_f32_16x16x32_bf16(a0, b0, acc00, 0, 0, 0);
        acc01 = __builtin_amdgcn_mfma_f32_16x16x32_bf16(a0, b1, acc01, 0, 0, 0);
        acc10 = __builtin_amdgcn_mfma_f32_16x16x32_bf16(a1, b0, acc10, 0, 0, 0);
        acc11 = __builtin_amdgcn_mfma_f32_16x16x32_bf16(a1, b1, acc11, 0, 0, 0);
    }

    const long long cz = (long long)z * sC;
    const int rbase = m0 + wr * 32 + fg * 4;
    const int cbase = n0 + wc * 32 + fr;
    auto emit = [&](f32x4 a, int mi, int ni) {
        int cc = cbase + ni * 16;
        if (cc >= N) return;
        float bv = HB ? bias[cc] : 0.f;
        #pragma unroll
        for (int v = 0; v < 4; v++) {
            int rr = rbase + mi * 16 + v;
            if (rr >= M) continue;
            float val = a[v] + bv;
            if (HR) val += R[(long long)z * sR + (long long)rr * ldr + cc];
            if (OB) ((short*)Cv)[cz + (long long)rr * ldc + cc] = f2b(val);
            else    ((float*)Cv)[cz + (long long)rr * ldc + cc] = val;
        }
    };
    emit(acc00, 0, 0); emit(acc01, 0, 1); emit(acc10, 1, 0); emit(acc11, 1, 1);
}

// ---------------------------------------------------------------------------
// Split-K SR-conv GEMM: gathers 8x8 patches from LNF on the fly.
// PART[z][1568][128] f32, z = 32 K-chunks of 256.
// ---------------------------------------------------------------------------
__global__ __launch_bounds__(256)
void srgemm(const short* __restrict__ LNF, const short* __restrict__ Wt,
            float* __restrict__ PART)
{
    __shared__ short As[2048];
    __shared__ short Bs[2048];
    const int z = blockIdx.z;
    const int m0 = blockIdx.y * 64, n0 = blockIdx.x * 64;
    const int tid = threadIdx.x, lane = tid & 63, wv = tid >> 6;
    const int wr = wv >> 1, wc = wv & 1;
    const int lrow = tid >> 2, lch = tid & 3;
    const int wch = lch ^ (lrow & 3);

    f32x4 zero = {0.f, 0.f, 0.f, 0.f};
    f32x4 acc00 = zero, acc01 = zero, acc10 = zero, acc11 = zero;

    int row = m0 + lrow;
    int rc = row < 1568 ? row : 1567;
    int b = rc / 196, p = rc % 196;
    int oh = p / 14, ow = p % 14;
    int k0 = z * 256;
    int kh = k0 >> 10, koff = k0 & 1023;
    const short* arow = LNF + ((long long)(b * 12544 + (oh * 8 + kh) * 112 + ow * 8)) * 128
                        + koff + lch * 8;
    const short* brow = Wt + (long long)(n0 + lrow) * 8192 + k0 + lch * 8;
    short* asw = &As[lrow * 32 + wch * 8];
    short* bsw = &Bs[lrow * 32 + wch * 8];

    const int fr = lane & 15, fg = lane >> 4;
    const int c = ((fg ^ (fr & 3)) * 8);
    const int a0off = (wr * 32 + fr) * 32 + c;
    const int b0off = (wc * 32 + fr) * 32 + c;

    for (int kk = 0; kk < 256; kk += 32) {
        uint4 av = *(const uint4*)arow; arow += 32;
        uint4 bv = *(const uint4*)brow; brow += 32;
        __syncthreads();
        *(uint4*)asw = av;
        *(uint4*)bsw = bv;
        __syncthreads();
        bf16x8 a0 = *(const bf16x8*)&As[a0off];
        bf16x8 a1 = *(const bf16x8*)&As[a0off + 512];
        bf16x8 b0 = *(const bf16x8*)&Bs[b0off];
        bf16x8 b1 = *(const bf16x8*)&Bs[b0off + 512];
        acc00 = __builtin_amdgcn_mfma_f32_16x16x32_bf16(a0, b0, acc00, 0, 0, 0);
        acc01 = __builtin_amdgcn_mfma_f32_16x16x32_bf16(a0, b1, acc01, 0, 0, 0);
        acc10 = __builtin_amdgcn_mfma_f32_16x16x32_bf16(a1, b0, acc10, 0, 0, 0);
        acc11 = __builtin_amdgcn_mfma_f32_16x16x32_bf16(a1, b1, acc11, 0, 0, 0);
    }

    const int rbase = m0 + wr * 32 + fg * 4;
    const int cbase = n0 + wc * 32 + fr;
    auto emit = [&](f32x4 a, int mi, int ni) {
        int cc = cbase + ni * 16;
        #pragma unroll
        for (int v = 0; v < 4; v++) {
            int rr = rbase + mi * 16 + v;
            if (rr >= 1568) continue;
            PART[(long long)z * 200704 + (long long)rr * 128 + cc] = a[v];
        }
    };
    emit(acc00, 0, 0); emit(acc01, 0, 1); emit(acc10, 1, 0); emit(acc11, 1, 1);
}

__global__ void reduceXS(const float* __restrict__ PART, const float* __restrict__ bias,
                         float* __restrict__ XS)
{
    int i = blockIdx.x * 256 + threadIdx.x;  // 200704 total
    float s = 0.f;
    #pragma unroll
    for (int z = 0; z < 32; z++) s += PART[(long long)z * 200704 + i];
    XS[i] = s + bias[i & 127];
}

// ---------------------------------------------------------------------------
// LayerNorm over C=128: f32 in -> bf16 out. One wave per row.
// ---------------------------------------------------------------------------
__global__ __launch_bounds__(256)
void ln_kernel(const float* __restrict__ x, const float* __restrict__ g,
               const float* __restrict__ b, short* __restrict__ o, int rows)
{
    int row = blockIdx.x * 4 + (threadIdx.x >> 6);
    if (row >= rows) return;
    int lane = threadIdx.x & 63;
    const float2 v = *(const float2*)&x[(long long)row * 128 + lane * 2];
    float s = v.x + v.y;
    float ss = v.x * v.x + v.y * v.y;
    #pragma unroll
    for (int off = 1; off < 64; off <<= 1) {
        s += __shfl_xor(s, off);
        ss += __shfl_xor(ss, off);
    }
    float mu = s * 0.0078125f;
    float var = ss * 0.0078125f - mu * mu;
    float rs = rsqrtf(var + 1e-5f);
    float2 gg = *(const float2*)&g[lane * 2];
    float2 bb = *(const float2*)&b[lane * 2];
    short2 out;
    out.x = f2b((v.x - mu) * rs * gg.x + bb.x);
    out.y = f2b((v.y - mu) * rs * gg.y + bb.y);
    *(short2*)&o[(long long)row * 128 + lane * 2] = out;
}

// f32 [K][N] -> bf16 [N][K]
__global__ void wtrans(const float* __restrict__ w, short* __restrict__ wt, int K, int N)
{
    long long idx = (long long)blockIdx.x * 256 + threadIdx.x;
    if (idx >= (long long)K * N) return;
    int k = (int)(idx / N), n = (int)(idx % N);
    wt[(long long)n * K + k] = f2b(w[idx]);
}

// ---------------------------------------------------------------------------
// Local windowed attention, all batches: block = (batch, window), 4 heads.
// ---------------------------------------------------------------------------
__global__ __launch_bounds__(256)
void lattn(const short* __restrict__ qkv, short* __restrict__ att)
{
    __shared__ float sm[49 * 33 * 3 + 49 * 50];
    float* qs = sm;
    float* ks = sm + 1617;
    float* vs = sm + 3234;
    float* S  = sm + 4851;
    const int bi = blockIdx.x >> 8;
    const int win = blockIdx.x & 255;
    const int wy = win >> 4, wx = win & 15;
    const long long base = (long long)bi * 12544;
    const int tid = threadIdx.x;
    const int lane = tid & 63, wvi = tid >> 6;

    for (int h = 0; h < 4; h++) {
        for (int idx = tid; idx < 588; idx += 256) {
            int arr = idx / 196, rem = idx % 196;
            int i = rem >> 2, dg = rem & 3;
            long long n = base + (wy * 7 + i / 7) * 112 + wx * 7 + i % 7;
            short8 v = *(const short8*)&qkv[n * 384 + arr * 128 + h * 32 + dg * 8];
            float* dst = (arr == 0) ? qs : (arr == 1) ? ks : vs;
            #pragma unroll
            for (int u = 0; u < 8; u++) dst[i * 33 + dg * 8 + u] = b2f(v[u]);
        }
        __syncthreads();
        for (int idx = tid; idx < 343; idx += 256) {
            int i = idx / 7, jg = idx % 7;
            int j0 = jg * 8, jn = (jg == 6) ? 1 : 8;
            float s[8] = {0, 0, 0, 0, 0, 0, 0, 0};
            for (int d = 0; d < 32; d++) {
                float qv = qs[i * 33 + d];
                #pragma unroll
                for (int u = 0; u < 8; u++) s[u] += qv * ks[(j0 + u) * 33 + d];
            }
            for (int u = 0; u < jn; u++) S[i * 50 + j0 + u] = s[u] * 0.17677669529663689f;
        }
        __syncthreads();
        for (int r = wvi; r < 49; r += 4) {
            float v = (lane < 49) ? S[r * 50 + lane] : -1e30f;
            float mx = v;
            #pragma unroll
            for (int off = 1; off < 64; off <<= 1) mx = fmaxf(mx, __shfl_xor(mx, off));
            float e = (lane < 49) ? __expf(v - mx) : 0.f;
            float sum = e;
            #pragma unroll
            for (int off = 1; off < 64; off <<= 1) sum += __shfl_xor(sum, off);
            if (lane < 49) S[r * 50 + lane] = e / sum;
        }
        __syncthreads();
        for (int idx = tid; idx < 196; idx += 256) {
            int i = idx >> 2, dg = idx & 3, d0 = dg * 8;
            float o[8] = {0, 0, 0, 0, 0, 0, 0, 0};
            for (int j = 0; j < 49; j++) {
                float p = S[i * 50 + j];
                #pragma unroll
                for (int u = 0; u < 8; u++) o[u] += p * vs[j * 33 + d0 + u];
            }
            long long n = base + (wy * 7 + i / 7) * 112 + wx * 7 + i % 7;
            short8 ov;
            #pragma unroll
            for (int u = 0; u < 8; u++) ov[u] = f2b(o[u]);
            *(short8*)&att[n * 128 + h * 32 + d0] = ov;
        }
        __syncthreads();
    }
}

// ---------------------------------------------------------------------------
// Fused global attention: per (q-block of 64, batch*head). K/V in LDS.
// Q: [B*12544][128] bf16, KVB: [1568][256] bf16, O: [B*12544][128] bf16.
// ---------------------------------------------------------------------------
__global__ __launch_bounds__(256)
void gattn(const short* __restrict__ Q, const short* __restrict__ KVB,
           short* __restrict__ O)
{
    __shared__ short Ks[208 * 40];      // key-major, stride 40
    __shared__ short Vt[32 * 232];      // dim-major (V^T), stride 232
    __shared__ short Pl[4 * 16 * 232];  // per-wave P rows, stride 232
    __shared__ float sums[4][16];
    const int qb = blockIdx.x;          // 0..195
    const int bh = blockIdx.y;          // 0..31
    const int b = bh >> 2, h = bh & 3;
    const int tid = threadIdx.x, w = tid >> 6, l = tid & 63;
    const int q16 = l & 15, g = l >> 4;

    for (int i = tid * 2; i < 208 * 40; i += 512) *(int*)&Ks[i] = 0;
    for (int i = tid * 2; i < 32 * 232; i += 512) *(int*)&Vt[i] = 0;
    __syncthreads();

    const long long kvbase = (long long)(b * 196) * 256 + h * 32;
    for (int idx = tid; idx < 784; idx += 256) {
        int m = idx >> 2, dg = idx & 3;
        uint4 v = *(const uint4*)&KVB[kvbase + (long long)m * 256 + dg * 8];
        *(uint4*)&Ks[m * 40 + dg * 8] = v;
    }
    for (int idx = tid; idx < 6272; idx += 256) {
        int m = idx >> 5, d = idx & 31;
        Vt[d * 232 + m] = KVB[kvbase + (long long)m * 256 + 128 + d];
    }
    const long long qrow = (long long)b * 12544 + qb * 64 + w * 16 + q16;
    bf16x8 qf = *(const bf16x8*)&Q[qrow * 128 + h * 32 + g * 8];
    __syncthreads();

    f32x4 zero = {0.f, 0.f, 0.f, 0.f};
    f32x4 s[13];
    #pragma unroll
    for (int t = 0; t < 13; t++) {
        bf16x8 a = *(const bf16x8*)&Ks[(t * 16 + q16) * 40 + g * 8];
        s[t] = __builtin_amdgcn_mfma_f32_16x16x32_bf16(a, qf, zero, 0, 0, 0);
    }
    const float SC = 0.17677669529663689f;
    float mx = -1e30f;
    #pragma unroll
    for (int t = 0; t < 13; t++) {
        #pragma unroll
        for (int v = 0; v < 4; v++) {
            int k = t * 16 + g * 4 + v;
            if (k < 196) mx = fmaxf(mx, s[t][v]);
        }
    }
    mx = fmaxf(mx, __shfl_xor(mx, 16));
    mx = fmaxf(mx, __shfl_xor(mx, 32));
    float sum = 0.f;
    #pragma unroll
    for (int t = 0; t < 13; t++) {
        #pragma unroll
        for (int v = 0; v < 4; v++) {
            int k = t * 16 + g * 4 + v;
            float pv = (k < 196) ? __expf(SC * (s[t][v] - mx)) : 0.f;
            s[t][v] = pv;
            sum += pv;
        }
    }
    sum += __shfl_xor(sum, 16);
    sum += __shfl_xor(sum, 32);
    if (g == 0) sums[w][q16] = 1.f / sum;

    short* pw = &Pl[(w * 16 + q16) * 232];
    #pragma unroll
    for (int t = 0; t < 13; t++) {
        int lo = ((int)(unsigned short)f2b(s[t][1]) << 16) | (unsigned short)f2b(s[t][0]);
        int hi = ((int)(unsigned short)f2b(s[t][3]) << 16) | (unsigned short)f2b(s[t][2]);
        int2 pr; pr.x = lo; pr.y = hi;
        *(int2*)&pw[t * 16 + g * 4] = pr;
    }
    int2 zz; zz.x = 0; zz.y = 0;
    *(int2*)&pw[208 + g * 4] = zz;
    __syncthreads();

    f32x4 o0 = zero, o1 = zero;
    #pragma unroll
    for (int kc = 0; kc < 7; kc++) {
        bf16x8 pa = *(const bf16x8*)&Pl[(w * 16 + q16) * 232 + kc * 32 + g * 8];
        bf16x8 v0 = *(const bf16x8*)&Vt[q16 * 232 + kc * 32 + g * 8];
        bf16x8 v1 = *(const bf16x8*)&Vt[(16 + q16) * 232 + kc * 32 + g * 8];
        o0 = __builtin_amdgcn_mfma_f32_16x16x32_bf16(pa, v0, o0, 0, 0, 0);
        o1 = __builtin_amdgcn_mfma_f32_16x16x32_bf16(pa, v1, o1, 0, 0, 0);
    }
    float sv[4];
    #pragma unroll
    for (int v = 0; v < 4; v++) sv[v] = sums[w][g * 4 + v];
    const long long obase = ((long long)b * 12544 + qb * 64 + w * 16) * 128 + h * 32;
    #pragma unroll
    for (int v = 0; v < 4; v++) {
        int qv = g * 4 + v;
        O[obase + (long long)qv * 128 + q16]      = f2b(o0[v] * sv[v]);
        O[obase + (long long)qv * 128 + 16 + q16] = f2b(o1[v] * sv[v]);
    }
}

// ---------------------------------------------------------------------------
// Depthwise 3x3 conv (SAME) + bias + exact GELU, multi-image.
// ---------------------------------------------------------------------------
__global__ __launch_bounds__(256)
void dwgelu(const short* __restrict__ h1, const float* __restrict__ w,
            const float* __restrict__ bias, short* __restrict__ h2)
{
    int idx = blockIdx.x * 256 + threadIdx.x;
    int cb = idx & 63, pix = idx >> 6;
    int img = pix / 12544, p = pix % 12544;
    int x = p % 112, y = p / 112;
    int c0 = cb << 3;
    float acc[8];
    #pragma unroll
    for (int u = 0; u < 8; u++) acc[u] = bias[c0 + u];
    for (int ky = 0; ky < 3; ky++) {
        int yy = y + ky - 1;
        if (yy < 0 || yy >= 112) continue;
        for (int kx = 0; kx < 3; kx++) {
            int xx = x + kx - 1;
            if (xx < 0 || xx >= 112) continue;
            short8 v = *(const short8*)&h1[((long long)img * 12544 + yy * 112 + xx) * 512 + c0];
            const float* wp = &w[(ky * 3 + kx) * 512 + c0];
            #pragma unroll
            for (int u = 0; u < 8; u++) acc[u] += b2f(v[u]) * wp[u];
        }
    }
    short8 ov;
    #pragma unroll
    for (int u = 0; u < 8; u++) {
        float a = acc[u];
        ov[u] = f2b(0.5f * a * (1.f + erff(a * 0.7071067811865475f)));
    }
    *(short8*)&h2[(long long)pix * 512 + c0] = ov;
}

// ---------------------------------------------------------------------------
extern "C" void kernel_launch(void* const* d_in, const int* in_sizes, int n_in,
                              void* d_out, int out_size, void* d_ws, size_t ws_size,
                              hipStream_t stream)
{
    (void)in_sizes; (void)n_in; (void)out_size;
    const float* X      = (const float*)d_in[0];
    const float* l_n1_g = (const float*)d_in[1];
    const float* l_n1_b = (const float*)d_in[2];
    const float* l_qkv_w= (const float*)d_in[3];
    const float* l_qkv_b= (const float*)d_in[4];
    const float* l_pw   = (const float*)d_in[5];
    const float* l_pb   = (const float*)d_in[6];
    const float* l_n2_g = (const float*)d_in[7];
    const float* l_n2_b = (const float*)d_in[8];
    const float* l_f1w  = (const float*)d_in[9];
    const float* l_f1b  = (const float*)d_in[10];
    const float* l_dww  = (const float*)d_in[11];
    const float* l_dwb  = (const float*)d_in[12];
    const float* l_f2w  = (const float*)d_in[13];
    const float* l_f2b  = (const float*)d_in[14];
    const float* g_n1_g = (const float*)d_in[15];
    const float* g_n1_b = (const float*)d_in[16];
    const float* g_qw   = (const float*)d_in[17];
    const float* g_qb   = (const float*)d_in[18];
    const float* g_kvw  = (const float*)d_in[19];
    const float* g_kvb  = (const float*)d_in[20];
    const float* g_srw  = (const float*)d_in[21];
    const float* g_srb  = (const float*)d_in[22];
    const float* g_sng  = (const float*)d_in[23];
    const float* g_snb  = (const float*)d_in[24];
    const float* g_pw   = (const float*)d_in[25];
    const float* g_pb   = (const float*)d_in[26];
    const float* g_n2_g = (const float*)d_in[27];
    const float* g_n2_b = (const float*)d_in[28];
    const float* g_f1w  = (const float*)d_in[29];
    const float* g_f1b  = (const float*)d_in[30];
    const float* g_dww  = (const float*)d_in[31];
    const float* g_dwb  = (const float*)d_in[32];
    const float* g_f2w  = (const float*)d_in[33];
    const float* g_f2b  = (const float*)d_in[34];

    const long long NPB = 12544;
    const long long BN  = 100352;
    const int iBN = (int)BN;

    float* OUT = (float*)d_out;
    char* ws = (char*)d_ws;
    size_t off = 0;
    auto alloc = [&](size_t bytes) { size_t o = off; off += (bytes + 255) & ~(size_t)255; return o; };
    short* WT_QKV = (short*)(ws + alloc(384 * 128 * 2));
    short* WT_LPW = (short*)(ws + alloc(128 * 128 * 2));
    short* WT_LF1 = (short*)(ws + alloc(512 * 128 * 2));
    short* WT_LF2 = (short*)(ws + alloc(128 * 512 * 2));
    short* WT_GQ  = (short*)(ws + alloc(128 * 128 * 2));
    short* WT_GKV = (short*)(ws + alloc(256 * 128 * 2));
    short* WT_GSR = (short*)(ws + alloc(128 * 8192 * 2));
    short* WT_GPW = (short*)(ws + alloc(128 * 128 * 2));
    short* WT_GF1 = (short*)(ws + alloc(512 * 128 * 2));
    short* WT_GF2 = (short*)(ws + alloc(128 * 512 * 2));
    short* LNF    = (short*)(ws + alloc((size_t)BN * 128 * 2));
    char*  U      = ws + alloc(0);

    // Phase-overlaid U region layout:
    const size_t SZ_H1   = (size_t)BN * 512 * 2;          // 102760448 (big path)
    const bool big = ws_size >= off + 2 * SZ_H1 + 4096;
    short* QKVB = (short*)(U + 0);                        // local attn
    short* ATT  = (short*)(U + 77070336);                 // both attn phases
    float* PART = (float*)(U + 0);                        // global phase
    float* XS   = (float*)(U + 25690368);
    short* XSLN = (short*)(U + 26493184);
    short* KVB  = (short*)(U + 26894592);
    short* QBUF = (short*)(U + 27697408);
    // MLP phase: H1 at U+0, H2 after (size depends on chunk)

    // weight transposes -> bf16 [N][K]
    wtrans<<<192, 256, 0, stream>>>(l_qkv_w, WT_QKV, 128, 384);
    wtrans<<<64, 256, 0, stream>>>(l_pw, WT_LPW, 128, 128);
    wtrans<<<256, 256, 0, stream>>>(l_f1w, WT_LF1, 128, 512);
    wtrans<<<256, 256, 0, stream>>>(l_f2w, WT_LF2, 512, 128);
    wtrans<<<64, 256, 0, stream>>>(g_qw, WT_GQ, 128, 128);
    wtrans<<<128, 256, 0, stream>>>(g_kvw, WT_GKV, 128, 256);
    wtrans<<<4096, 256, 0, stream>>>(g_srw, WT_GSR, 8192, 128);
    wtrans<<<64, 256, 0, stream>>>(g_pw, WT_GPW, 128, 128);
    wtrans<<<256, 256, 0, stream>>>(g_f1w, WT_GF1, 128, 512);
    wtrans<<<256, 256, 0, stream>>>(g_f2w, WT_GF2, 512, 128);

    const int CB = big ? 8 : 2;  // MLP batch chunk
    short* H1 = (short*)(U + 0);

    // ---------------- Local attention block ----------------
    ln_kernel<<<25088, 256, 0, stream>>>(X, l_n1_g, l_n1_b, LNF, iBN);
    gemm64<1, 1, 0><<<dim3(6, 1568, 1), 256, 0, stream>>>(
        LNF, 128, 0, WT_QKV, 128, 0, l_qkv_b,
        QKVB, 384, 0, nullptr, 0, 0, iBN, 384, 128);
    lattn<<<2048, 256, 0, stream>>>(QKVB, ATT);
    gemm64<0, 1, 1><<<dim3(2, 1568, 1), 256, 0, stream>>>(
        ATT, 128, 0, WT_LPW, 128, 0, l_pb,
        OUT, 128, 0, X, 128, 0, iBN, 128, 128);

    // ---------------- Local MLP block ----------------
    ln_kernel<<<25088, 256, 0, stream>>>(OUT, l_n2_g, l_n2_b, LNF, iBN);
    {
        short* H2 = (short*)(U + (size_t)CB * NPB * 512 * 2);
        for (int b0 = 0; b0 < 8; b0 += CB) {
            int Mc = CB * 12544;
            gemm64<1, 1, 0><<<dim3(8, Mc / 64, 1), 256, 0, stream>>>(
                LNF + (long long)b0 * NPB * 128, 128, 0, WT_LF1, 128, 0, l_f1b,
                H1, 512, 0, nullptr, 0, 0, Mc, 512, 128);
            dwgelu<<<Mc / 4, 256, 0, stream>>>(H1, l_dww, l_dwb, H2);
            gemm64<0, 1, 1><<<dim3(2, Mc / 64, 1), 256, 0, stream>>>(
                H2, 512, 0, WT_LF2, 512, 0, l_f2b,
                OUT + (long long)b0 * NPB * 128, 128, 0,
                OUT + (long long)b0 * NPB * 128, 128, 0, Mc, 128, 512);
        }
    }

    // ---------------- Global attention block ----------------
    ln_kernel<<<25088, 256, 0, stream>>>(OUT, g_n1_g, g_n1_b, LNF, iBN);
    gemm64<1, 1, 0><<<dim3(2, 1568, 1), 256, 0, stream>>>(
        LNF, 128, 0, WT_GQ, 128, 0, g_qb,
        QBUF, 128, 0, nullptr, 0, 0, iBN, 128, 128);
    srgemm<<<dim3(2, 25, 32), 256, 0, stream>>>(LNF, WT_GSR, PART);
    reduceXS<<<784, 256, 0, stream>>>(PART, g_srb, XS);
    ln_kernel<<<392, 256, 0, stream>>>(XS, g_sng, g_snb, XSLN, 1568);
    gemm64<1, 1, 0><<<dim3(4, 25, 1), 256, 0, stream>>>(
        XSLN, 128, 0, WT_GKV, 128, 0, g_kvb,
        KVB, 256, 0, nullptr, 0, 0, 1568, 256, 128);
    gattn<<<dim3(196, 32), 256, 0, stream>>>(QBUF, KVB, ATT);
    gemm64<0, 1, 1><<<dim3(2, 1568, 1), 256, 0, stream>>>(
        ATT, 128, 0, WT_GPW, 128, 0, g_pb,
        OUT, 128, 0, OUT, 128, 0, iBN, 128, 128);

    // ---------------- Global MLP block ----------------
    ln_kernel<<<25088, 256, 0, stream>>>(OUT, g_n2_g, g_n2_b, LNF, iBN);
    {
        short* H2 = (short*)(U + (size_t)CB * NPB * 512 * 2);
        for (int b0 = 0; b0 < 8; b0 += CB) {
            int Mc = CB * 12544;
            gemm64<1, 1, 0><<<dim3(8, Mc / 64, 1), 256, 0, stream>>>(
                LNF + (long long)b0 * NPB * 128, 128, 0, WT_GF1, 128, 0, g_f1b,
                H1, 512, 0, nullptr, 0, 0, Mc, 512, 128);
            dwgelu<<<Mc / 4, 256, 0, stream>>>(H1, g_dww, g_dwb, H2);
            gemm64<0, 1, 1><<<dim3(2, Mc / 64, 1), 256, 0, stream>>>(
                H2, 512, 0, WT_GF2, 512, 0, g_f2b,
                OUT + (long long)b0 * NPB * 128, 128, 0,
                OUT + (long long)b0 * NPB * 128, 128, 0, Mc, 128, 512);
        }
    }
}

// Round 3
// 825.692 us; speedup vs baseline: 2.1824x; 1.2865x over previous
//
#include <hip/hip_runtime.h>
#include <hip/hip_bf16.h>

#define DI __device__ __forceinline__

typedef __attribute__((ext_vector_type(8))) __bf16 bf16x8;
typedef __attribute__((ext_vector_type(8))) short short8;
typedef __attribute__((ext_vector_type(4))) float f32x4;

DI short f2b(float f) {
    union { float f; unsigned u; } v; v.f = f;
    unsigned r = v.u + 0x7FFFu + ((v.u >> 16) & 1u);
    return (short)(r >> 16);
}
DI float b2f(short s) {
    union { unsigned u; float f; } v; v.u = ((unsigned)(unsigned short)s) << 16;
    return v.f;
}

// ---------------------------------------------------------------------------
// Generic 64x64 MFMA bf16 GEMM: C[M][N] = A[M][K] @ Wt[N][K]^T (+bias) (+resid)
// ---------------------------------------------------------------------------
template<int OB, int HB, int HR>
__global__ __launch_bounds__(256)
void gemm64(const short* __restrict__ A, int lda, long long sA,
            const short* __restrict__ Wt, int ldw, long long sW,
            const float* __restrict__ bias,
            void* __restrict__ Cv, int ldc, long long sC,
            const float* __restrict__ R, int ldr, long long sR,
            int M, int N, int K)
{
    __shared__ short As[2048];
    __shared__ short Bs[2048];
    const int z = blockIdx.z;
    A  += (long long)z * sA;
    Wt += (long long)z * sW;
    const int m0 = blockIdx.y * 64, n0 = blockIdx.x * 64;
    const int tid = threadIdx.x, lane = tid & 63, wv = tid >> 6;
    const int wr = wv >> 1, wc = wv & 1;
    const int lrow = tid >> 2, lch = tid & 3;
    const int wch = lch ^ (lrow & 3);

    f32x4 zero = {0.f, 0.f, 0.f, 0.f};
    f32x4 acc00 = zero, acc01 = zero, acc10 = zero, acc11 = zero;

    const short* arow = &A[(long long)(m0 + lrow) * lda + lch * 8];
    const short* brow = &Wt[(long long)(n0 + lrow) * ldw + lch * 8];
    short* asw = &As[lrow * 32 + wch * 8];
    short* bsw = &Bs[lrow * 32 + wch * 8];

    const int fr = lane & 15, fg = lane >> 4;
    const int c = ((fg ^ (fr & 3)) * 8);
    const int a0off = (wr * 32 + fr) * 32 + c;
    const int b0off = (wc * 32 + fr) * 32 + c;

    for (int k0 = 0; k0 < K; k0 += 32) {
        uint4 av = *(const uint4*)arow; arow += 32;
        uint4 bv = *(const uint4*)brow; brow += 32;
        __syncthreads();
        *(uint4*)asw = av;
        *(uint4*)bsw = bv;
        __syncthreads();
        bf16x8 a0 = *(const bf16x8*)&As[a0off];
        bf16x8 a1 = *(const bf16x8*)&As[a0off + 512];
        bf16x8 b0 = *(const bf16x8*)&Bs[b0off];
        bf16x8 b1 = *(const bf16x8*)&Bs[b0off + 512];
        acc00 = __builtin_amdgcn_mfma_f32_16x16x32_bf16(a0, b0, acc00, 0, 0, 0);
        acc01 = __builtin_amdgcn_mfma_f32_16x16x32_bf16(a0, b1, acc01, 0, 0, 0);
        acc10 = __builtin_amdgcn_mfma_f32_16x16x32_bf16(a1, b0, acc10, 0, 0, 0);
        acc11 = __builtin_amdgcn_mfma_f32_16x16x32_bf16(a1, b1, acc11, 0, 0, 0);
    }

    const long long cz = (long long)z * sC;
    const int rbase = m0 + wr * 32 + fg * 4;
    const int cbase = n0 + wc * 32 + fr;
    auto emit = [&](f32x4 a, int mi, int ni) {
        int cc = cbase + ni * 16;
        if (cc >= N) return;
        float bv = HB ? bias[cc] : 0.f;
        #pragma unroll
        for (int v = 0; v < 4; v++) {
            int rr = rbase + mi * 16 + v;
            if (rr >= M) continue;
            float val = a[v] + bv;
            if (HR) val += R[(long long)z * sR + (long long)rr * ldr + cc];
            if (OB) ((short*)Cv)[cz + (long long)rr * ldc + cc] = f2b(val);
            else    ((float*)Cv)[cz + (long long)rr * ldc + cc] = val;
        }
    };
    emit(acc00, 0, 0); emit(acc01, 0, 1); emit(acc10, 1, 0); emit(acc11, 1, 1);
}

// ---------------------------------------------------------------------------
// Split-K SR-conv GEMM: gathers 8x8 patches from LNF on the fly.
// PART[z][1568][128] f32, z = 32 K-chunks of 256.
// ---------------------------------------------------------------------------
__global__ __launch_bounds__(256)
void srgemm(const short* __restrict__ LNF, const short* __restrict__ Wt,
            float* __restrict__ PART)
{
    __shared__ short As[2048];
    __shared__ short Bs[2048];
    const int z = blockIdx.z;
    const int m0 = blockIdx.y * 64, n0 = blockIdx.x * 64;
    const int tid = threadIdx.x, lane = tid & 63, wv = tid >> 6;
    const int wr = wv >> 1, wc = wv & 1;
    const int lrow = tid >> 2, lch = tid & 3;
    const int wch = lch ^ (lrow & 3);

    f32x4 zero = {0.f, 0.f, 0.f, 0.f};
    f32x4 acc00 = zero, acc01 = zero, acc10 = zero, acc11 = zero;

    int row = m0 + lrow;
    int rc = row < 1568 ? row : 1567;
    int b = rc / 196, p = rc % 196;
    int oh = p / 14, ow = p % 14;
    int k0 = z * 256;
    int kh = k0 >> 10, koff = k0 & 1023;
    const short* arow = LNF + ((long long)(b * 12544 + (oh * 8 + kh) * 112 + ow * 8)) * 128
                        + koff + lch * 8;
    const short* brow = Wt + (long long)(n0 + lrow) * 8192 + k0 + lch * 8;
    short* asw = &As[lrow * 32 + wch * 8];
    short* bsw = &Bs[lrow * 32 + wch * 8];

    const int fr = lane & 15, fg = lane >> 4;
    const int c = ((fg ^ (fr & 3)) * 8);
    const int a0off = (wr * 32 + fr) * 32 + c;
    const int b0off = (wc * 32 + fr) * 32 + c;

    for (int kk = 0; kk < 256; kk += 32) {
        uint4 av = *(const uint4*)arow; arow += 32;
        uint4 bv = *(const uint4*)brow; brow += 32;
        __syncthreads();
        *(uint4*)asw = av;
        *(uint4*)bsw = bv;
        __syncthreads();
        bf16x8 a0 = *(const bf16x8*)&As[a0off];
        bf16x8 a1 = *(const bf16x8*)&As[a0off + 512];
        bf16x8 b0 = *(const bf16x8*)&Bs[b0off];
        bf16x8 b1 = *(const bf16x8*)&Bs[b0off + 512];
        acc00 = __builtin_amdgcn_mfma_f32_16x16x32_bf16(a0, b0, acc00, 0, 0, 0);
        acc01 = __builtin_amdgcn_mfma_f32_16x16x32_bf16(a0, b1, acc01, 0, 0, 0);
        acc10 = __builtin_amdgcn_mfma_f32_16x16x32_bf16(a1, b0, acc10, 0, 0, 0);
        acc11 = __builtin_amdgcn_mfma_f32_16x16x32_bf16(a1, b1, acc11, 0, 0, 0);
    }

    const int rbase = m0 + wr * 32 + fg * 4;
    const int cbase = n0 + wc * 32 + fr;
    auto emit = [&](f32x4 a, int mi, int ni) {
        int cc = cbase + ni * 16;
        #pragma unroll
        for (int v = 0; v < 4; v++) {
            int rr = rbase + mi * 16 + v;
            if (rr >= 1568) continue;
            PART[(long long)z * 200704 + (long long)rr * 128 + cc] = a[v];
        }
    };
    emit(acc00, 0, 0); emit(acc01, 0, 1); emit(acc10, 1, 0); emit(acc11, 1, 1);
}

__global__ void reduceXS(const float* __restrict__ PART, const float* __restrict__ bias,
                         float* __restrict__ XS)
{
    int i = blockIdx.x * 256 + threadIdx.x;  // 200704 total
    float s = 0.f;
    #pragma unroll
    for (int z = 0; z < 32; z++) s += PART[(long long)z * 200704 + i];
    XS[i] = s + bias[i & 127];
}

// ---------------------------------------------------------------------------
// LayerNorm over C=128: f32 in -> bf16 out. One wave per row.
// ---------------------------------------------------------------------------
__global__ __launch_bounds__(256)
void ln_kernel(const float* __restrict__ x, const float* __restrict__ g,
               const float* __restrict__ b, short* __restrict__ o, int rows)
{
    int row = blockIdx.x * 4 + (threadIdx.x >> 6);
    if (row >= rows) return;
    int lane = threadIdx.x & 63;
    const float2 v = *(const float2*)&x[(long long)row * 128 + lane * 2];
    float s = v.x + v.y;
    float ss = v.x * v.x + v.y * v.y;
    #pragma unroll
    for (int off = 1; off < 64; off <<= 1) {
        s += __shfl_xor(s, off);
        ss += __shfl_xor(ss, off);
    }
    float mu = s * 0.0078125f;
    float var = ss * 0.0078125f - mu * mu;
    float rs = rsqrtf(var + 1e-5f);
    float2 gg = *(const float2*)&g[lane * 2];
    float2 bb = *(const float2*)&b[lane * 2];
    short2 out;
    out.x = f2b((v.x - mu) * rs * gg.x + bb.x);
    out.y = f2b((v.y - mu) * rs * gg.y + bb.y);
    *(short2*)&o[(long long)row * 128 + lane * 2] = out;
}

// f32 [K][N] -> bf16 [N][K]
__global__ void wtrans(const float* __restrict__ w, short* __restrict__ wt, int K, int N)
{
    long long idx = (long long)blockIdx.x * 256 + threadIdx.x;
    if (idx >= (long long)K * N) return;
    int k = (int)(idx / N), n = (int)(idx % N);
    wt[(long long)n * K + k] = f2b(w[idx]);
}

// ---------------------------------------------------------------------------
// Local windowed attention via MFMA. Block = (batch, window), 512 threads.
// 8 waves: wave w -> head (w>>1), q-half (w&1) (2 q-tiles of 16 each).
// S = mfma(K_frag, Q_frag) so softmax is lane-local over k; P -> bf16 LDS;
// PV = mfma(P_frag, Vt_frag) with group-XOR-swizzled V^T.
// ---------------------------------------------------------------------------
__global__ __launch_bounds__(512)
void lattn(const short* __restrict__ qkv, short* __restrict__ att)
{
    __shared__ short QKs[64 * 264];   // rows 0..48 valid: q cols 0..127, k cols 128..255
    __shared__ short Vt[128 * 72];    // V^T [c][k], col-group XOR swizzle
    __shared__ short Pl[8 * 16 * 72]; // per-wave P rows (16 q x 64 k)
    const int bi = blockIdx.x >> 8;
    const int win = blockIdx.x & 255;
    const int wy = win >> 4, wx = win & 15;
    const long long base = (long long)bi * 12544;
    const int tid = threadIdx.x;

    // zero Vt so padded k-columns (49..63) contribute exact 0 (P=0 * 0)
    for (int i = tid; i < 1152; i += 512) {
        uint4 zz = {0, 0, 0, 0};
        *(uint4*)&Vt[i * 8] = zz;
    }
    __syncthreads();

    // stage qkv rows: q,k row-major into QKs; v transposed+swizzled into Vt
    for (int idx = tid; idx < 2352; idx += 512) {
        int i = idx / 48, ch = idx % 48;
        long long n = base + (wy * 7 + i / 7) * 112 + wx * 7 + i % 7;
        uint4 v = *(const uint4*)&qkv[n * 384 + ch * 8];
        if (ch < 32) {
            *(uint4*)&QKs[i * 264 + ch * 8] = v;
        } else {
            int c0 = (ch - 32) * 8;
            const short* sp = (const short*)&v;
            #pragma unroll
            for (int u = 0; u < 8; u++) {
                int cc = c0 + u;
                Vt[cc * 72 + ((((i >> 3) ^ ((cc >> 3) & 7)) << 3) | (i & 7))] = sp[u];
            }
        }
    }
    __syncthreads();

    const int w = tid >> 6, l = tid & 63;
    const int h = w >> 1, qh = w & 1;
    const int q16 = l & 15, g = l >> 4;
    const float SC = 0.17677669529663689f;
    f32x4 zero = {0.f, 0.f, 0.f, 0.f};

    // K fragments: rows = k tokens, shared across q-tiles
    bf16x8 kf[4];
    #pragma unroll
    for (int kt = 0; kt < 4; kt++)
        kf[kt] = *(const bf16x8*)&QKs[(kt * 16 + q16) * 264 + 128 + h * 32 + g * 8];
    // V^T fragments: col entity = output dim
    bf16x8 vf[2][2];
    #pragma unroll
    for (int dt = 0; dt < 2; dt++) {
        int cc = h * 32 + dt * 16 + q16;
        #pragma unroll
        for (int s2 = 0; s2 < 2; s2++)
            vf[dt][s2] = *(const bf16x8*)&Vt[cc * 72 + (((s2 * 4 + g) ^ ((cc >> 3) & 7)) << 3)];
    }
    short* pw = &Pl[(w * 16 + q16) * 72];

    for (int qt2 = 0; qt2 < 2; qt2++) {
        int qt = qh * 2 + qt2;
        bf16x8 qf = *(const bf16x8*)&QKs[(qt * 16 + q16) * 264 + h * 32 + g * 8];
        f32x4 s[4];
        #pragma unroll
        for (int kt = 0; kt < 4; kt++)
            s[kt] = __builtin_amdgcn_mfma_f32_16x16x32_bf16(kf[kt], qf, zero, 0, 0, 0);
        // softmax over k for this lane's q column (col = q16, rows spread over g,v,kt)
        float mx = -1e30f;
        #pragma unroll
        for (int kt = 0; kt < 4; kt++) {
            #pragma unroll
            for (int v = 0; v < 4; v++) {
                int k = kt * 16 + g * 4 + v;
                if (k < 49) mx = fmaxf(mx, s[kt][v]);
            }
        }
        mx = fmaxf(mx, __shfl_xor(mx, 16));
        mx = fmaxf(mx, __shfl_xor(mx, 32));
        float sum = 0.f;
        #pragma unroll
        for (int kt = 0; kt < 4; kt++) {
            #pragma unroll
            for (int v = 0; v < 4; v++) {
                int k = kt * 16 + g * 4 + v;
                float p = (k < 49) ? __expf(SC * (s[kt][v] - mx)) : 0.f;
                s[kt][v] = p;
                sum += p;
            }
        }
        sum += __shfl_xor(sum, 16);
        sum += __shfl_xor(sum, 32);
        float inv = 1.f / sum;
        #pragma unroll
        for (int kt = 0; kt < 4; kt++) {
            int lo = ((int)(unsigned short)f2b(s[kt][1] * inv) << 16) | (unsigned short)f2b(s[kt][0] * inv);
            int hi = ((int)(unsigned short)f2b(s[kt][3] * inv) << 16) | (unsigned short)f2b(s[kt][2] * inv);
            int2 pr; pr.x = lo; pr.y = hi;
            *(int2*)&pw[kt * 16 + g * 4] = pr;
        }
        // PV (wave-private LDS; compiler inserts lgkmcnt, no barrier needed)
        f32x4 o0 = zero, o1 = zero;
        #pragma unroll
        for (int s2 = 0; s2 < 2; s2++) {
            bf16x8 pa = *(const bf16x8*)&pw[s2 * 32 + g * 8];
            o0 = __builtin_amdgcn_mfma_f32_16x16x32_bf16(pa, vf[0][s2], o0, 0, 0, 0);
            o1 = __builtin_amdgcn_mfma_f32_16x16x32_bf16(pa, vf[1][s2], o1, 0, 0, 0);
        }
        #pragma unroll
        for (int v = 0; v < 4; v++) {
            int q = qt * 16 + g * 4 + v;
            if (q < 49) {
                long long n = base + (wy * 7 + q / 7) * 112 + wx * 7 + q % 7;
                att[n * 128 + h * 32 + q16]      = f2b(o0[v]);
                att[n * 128 + h * 32 + 16 + q16] = f2b(o1[v]);
            }
        }
    }
}

// ---------------------------------------------------------------------------
// Fused global attention: per (q-block of 64, batch*head). K/V in LDS.
// ---------------------------------------------------------------------------
__global__ __launch_bounds__(256)
void gattn(const short* __restrict__ Q, const short* __restrict__ KVB,
           short* __restrict__ O)
{
    __shared__ short Ks[208 * 40];      // key-major, stride 40
    __shared__ short Vt[32 * 232];      // dim-major (V^T), stride 232
    __shared__ short Pl[4 * 16 * 232];  // per-wave P rows, stride 232
    __shared__ float sums[4][16];
    const int qb = blockIdx.x;          // 0..195
    const int bh = blockIdx.y;          // 0..31
    const int b = bh >> 2, h = bh & 3;
    const int tid = threadIdx.x, w = tid >> 6, l = tid & 63;
    const int q16 = l & 15, g = l >> 4;

    for (int i = tid * 2; i < 208 * 40; i += 512) *(int*)&Ks[i] = 0;
    for (int i = tid * 2; i < 32 * 232; i += 512) *(int*)&Vt[i] = 0;
    __syncthreads();

    const long long kvbase = (long long)(b * 196) * 256 + h * 32;
    for (int idx = tid; idx < 784; idx += 256) {
        int m = idx >> 2, dg = idx & 3;
        uint4 v = *(const uint4*)&KVB[kvbase + (long long)m * 256 + dg * 8];
        *(uint4*)&Ks[m * 40 + dg * 8] = v;
    }
    for (int idx = tid; idx < 6272; idx += 256) {
        int m = idx >> 5, d = idx & 31;
        Vt[d * 232 + m] = KVB[kvbase + (long long)m * 256 + 128 + d];
    }
    const long long qrow = (long long)b * 12544 + qb * 64 + w * 16 + q16;
    bf16x8 qf = *(const bf16x8*)&Q[qrow * 128 + h * 32 + g * 8];
    __syncthreads();

    f32x4 zero = {0.f, 0.f, 0.f, 0.f};
    f32x4 s[13];
    #pragma unroll
    for (int t = 0; t < 13; t++) {
        bf16x8 a = *(const bf16x8*)&Ks[(t * 16 + q16) * 40 + g * 8];
        s[t] = __builtin_amdgcn_mfma_f32_16x16x32_bf16(a, qf, zero, 0, 0, 0);
    }
    const float SC = 0.17677669529663689f;
    float mx = -1e30f;
    #pragma unroll
    for (int t = 0; t < 13; t++) {
        #pragma unroll
        for (int v = 0; v < 4; v++) {
            int k = t * 16 + g * 4 + v;
            if (k < 196) mx = fmaxf(mx, s[t][v]);
        }
    }
    mx = fmaxf(mx, __shfl_xor(mx, 16));
    mx = fmaxf(mx, __shfl_xor(mx, 32));
    float sum = 0.f;
    #pragma unroll
    for (int t = 0; t < 13; t++) {
        #pragma unroll
        for (int v = 0; v < 4; v++) {
            int k = t * 16 + g * 4 + v;
            float pv = (k < 196) ? __expf(SC * (s[t][v] - mx)) : 0.f;
            s[t][v] = pv;
            sum += pv;
        }
    }
    sum += __shfl_xor(sum, 16);
    sum += __shfl_xor(sum, 32);
    if (g == 0) sums[w][q16] = 1.f / sum;

    short* pw = &Pl[(w * 16 + q16) * 232];
    #pragma unroll
    for (int t = 0; t < 13; t++) {
        int lo = ((int)(unsigned short)f2b(s[t][1]) << 16) | (unsigned short)f2b(s[t][0]);
        int hi = ((int)(unsigned short)f2b(s[t][3]) << 16) | (unsigned short)f2b(s[t][2]);
        int2 pr; pr.x = lo; pr.y = hi;
        *(int2*)&pw[t * 16 + g * 4] = pr;
    }
    int2 zz; zz.x = 0; zz.y = 0;
    *(int2*)&pw[208 + g * 4] = zz;
    __syncthreads();

    f32x4 o0 = zero, o1 = zero;
    #pragma unroll
    for (int kc = 0; kc < 7; kc++) {
        bf16x8 pa = *(const bf16x8*)&Pl[(w * 16 + q16) * 232 + kc * 32 + g * 8];
        bf16x8 v0 = *(const bf16x8*)&Vt[q16 * 232 + kc * 32 + g * 8];
        bf16x8 v1 = *(const bf16x8*)&Vt[(16 + q16) * 232 + kc * 32 + g * 8];
        o0 = __builtin_amdgcn_mfma_f32_16x16x32_bf16(pa, v0, o0, 0, 0, 0);
        o1 = __builtin_amdgcn_mfma_f32_16x16x32_bf16(pa, v1, o1, 0, 0, 0);
    }
    float sv[4];
    #pragma unroll
    for (int v = 0; v < 4; v++) sv[v] = sums[w][g * 4 + v];
    const long long obase = ((long long)b * 12544 + qb * 64 + w * 16) * 128 + h * 32;
    #pragma unroll
    for (int v = 0; v < 4; v++) {
        int qv = g * 4 + v;
        O[obase + (long long)qv * 128 + q16]      = f2b(o0[v] * sv[v]);
        O[obase + (long long)qv * 128 + 16 + q16] = f2b(o1[v] * sv[v]);
    }
}

// ---------------------------------------------------------------------------
// Depthwise 3x3 conv (SAME) + bias + exact GELU, multi-image.
// ---------------------------------------------------------------------------
__global__ __launch_bounds__(256)
void dwgelu(const short* __restrict__ h1, const float* __restrict__ w,
            const float* __restrict__ bias, short* __restrict__ h2)
{
    int idx = blockIdx.x * 256 + threadIdx.x;
    int cb = idx & 63, pix = idx >> 6;
    int img = pix / 12544, p = pix % 12544;
    int x = p % 112, y = p / 112;
    int c0 = cb << 3;
    float acc[8];
    #pragma unroll
    for (int u = 0; u < 8; u++) acc[u] = bias[c0 + u];
    for (int ky = 0; ky < 3; ky++) {
        int yy = y + ky - 1;
        if (yy < 0 || yy >= 112) continue;
        for (int kx = 0; kx < 3; kx++) {
            int xx = x + kx - 1;
            if (xx < 0 || xx >= 112) continue;
            short8 v = *(const short8*)&h1[((long long)img * 12544 + yy * 112 + xx) * 512 + c0];
            const float* wp = &w[(ky * 3 + kx) * 512 + c0];
            #pragma unroll
            for (int u = 0; u < 8; u++) acc[u] += b2f(v[u]) * wp[u];
        }
    }
    short8 ov;
    #pragma unroll
    for (int u = 0; u < 8; u++) {
        float a = acc[u];
        ov[u] = f2b(0.5f * a * (1.f + erff(a * 0.7071067811865475f)));
    }
    *(short8*)&h2[(long long)pix * 512 + c0] = ov;
}

// ---------------------------------------------------------------------------
extern "C" void kernel_launch(void* const* d_in, const int* in_sizes, int n_in,
                              void* d_out, int out_size, void* d_ws, size_t ws_size,
                              hipStream_t stream)
{
    (void)in_sizes; (void)n_in; (void)out_size;
    const float* X      = (const float*)d_in[0];
    const float* l_n1_g = (const float*)d_in[1];
    const float* l_n1_b = (const float*)d_in[2];
    const float* l_qkv_w= (const float*)d_in[3];
    const float* l_qkv_b= (const float*)d_in[4];
    const float* l_pw   = (const float*)d_in[5];
    const float* l_pb   = (const float*)d_in[6];
    const float* l_n2_g = (const float*)d_in[7];
    const float* l_n2_b = (const float*)d_in[8];
    const float* l_f1w  = (const float*)d_in[9];
    const float* l_f1b  = (const float*)d_in[10];
    const float* l_dww  = (const float*)d_in[11];
    const float* l_dwb  = (const float*)d_in[12];
    const float* l_f2w  = (const float*)d_in[13];
    const float* l_f2b  = (const float*)d_in[14];
    const float* g_n1_g = (const float*)d_in[15];
    const float* g_n1_b = (const float*)d_in[16];
    const float* g_qw   = (const float*)d_in[17];
    const float* g_qb   = (const float*)d_in[18];
    const float* g_kvw  = (const float*)d_in[19];
    const float* g_kvb  = (const float*)d_in[20];
    const float* g_srw  = (const float*)d_in[21];
    const float* g_srb  = (const float*)d_in[22];
    const float* g_sng  = (const float*)d_in[23];
    const float* g_snb  = (const float*)d_in[24];
    const float* g_pw   = (const float*)d_in[25];
    const float* g_pb   = (const float*)d_in[26];
    const float* g_n2_g = (const float*)d_in[27];
    const float* g_n2_b = (const float*)d_in[28];
    const float* g_f1w  = (const float*)d_in[29];
    const float* g_f1b  = (const float*)d_in[30];
    const float* g_dww  = (const float*)d_in[31];
    const float* g_dwb  = (const float*)d_in[32];
    const float* g_f2w  = (const float*)d_in[33];
    const float* g_f2b  = (const float*)d_in[34];

    const long long NPB = 12544;
    const long long BN  = 100352;
    const int iBN = (int)BN;

    float* OUT = (float*)d_out;
    char* ws = (char*)d_ws;
    size_t off = 0;
    auto alloc = [&](size_t bytes) { size_t o = off; off += (bytes + 255) & ~(size_t)255; return o; };
    short* WT_QKV = (short*)(ws + alloc(384 * 128 * 2));
    short* WT_LPW = (short*)(ws + alloc(128 * 128 * 2));
    short* WT_LF1 = (short*)(ws + alloc(512 * 128 * 2));
    short* WT_LF2 = (short*)(ws + alloc(128 * 512 * 2));
    short* WT_GQ  = (short*)(ws + alloc(128 * 128 * 2));
    short* WT_GKV = (short*)(ws + alloc(256 * 128 * 2));
    short* WT_GSR = (short*)(ws + alloc(128 * 8192 * 2));
    short* WT_GPW = (short*)(ws + alloc(128 * 128 * 2));
    short* WT_GF1 = (short*)(ws + alloc(512 * 128 * 2));
    short* WT_GF2 = (short*)(ws + alloc(128 * 512 * 2));
    short* LNF    = (short*)(ws + alloc((size_t)BN * 128 * 2));
    char*  U      = ws + alloc(0);

    const size_t SZ_H1   = (size_t)BN * 512 * 2;
    const bool big = ws_size >= off + 2 * SZ_H1 + 4096;
    short* QKVB = (short*)(U + 0);
    short* ATT  = (short*)(U + 77070336);
    float* PART = (float*)(U + 0);
    float* XS   = (float*)(U + 25690368);
    short* XSLN = (short*)(U + 26493184);
    short* KVB  = (short*)(U + 26894592);
    short* QBUF = (short*)(U + 27697408);

    wtrans<<<192, 256, 0, stream>>>(l_qkv_w, WT_QKV, 128, 384);
    wtrans<<<64, 256, 0, stream>>>(l_pw, WT_LPW, 128, 128);
    wtrans<<<256, 256, 0, stream>>>(l_f1w, WT_LF1, 128, 512);
    wtrans<<<256, 256, 0, stream>>>(l_f2w, WT_LF2, 512, 128);
    wtrans<<<64, 256, 0, stream>>>(g_qw, WT_GQ, 128, 128);
    wtrans<<<128, 256, 0, stream>>>(g_kvw, WT_GKV, 128, 256);
    wtrans<<<4096, 256, 0, stream>>>(g_srw, WT_GSR, 8192, 128);
    wtrans<<<64, 256, 0, stream>>>(g_pw, WT_GPW, 128, 128);
    wtrans<<<256, 256, 0, stream>>>(g_f1w, WT_GF1, 128, 512);
    wtrans<<<256, 256, 0, stream>>>(g_f2w, WT_GF2, 512, 128);

    const int CB = big ? 8 : 2;
    short* H1 = (short*)(U + 0);

    // ---------------- Local attention block ----------------
    ln_kernel<<<25088, 256, 0, stream>>>(X, l_n1_g, l_n1_b, LNF, iBN);
    gemm64<1, 1, 0><<<dim3(6, 1568, 1), 256, 0, stream>>>(
        LNF, 128, 0, WT_QKV, 128, 0, l_qkv_b,
        QKVB, 384, 0, nullptr, 0, 0, iBN, 384, 128);
    lattn<<<2048, 512, 0, stream>>>(QKVB, ATT);
    gemm64<0, 1, 1><<<dim3(2, 1568, 1), 256, 0, stream>>>(
        ATT, 128, 0, WT_LPW, 128, 0, l_pb,
        OUT, 128, 0, X, 128, 0, iBN, 128, 128);

    // ---------------- Local MLP block ----------------
    ln_kernel<<<25088, 256, 0, stream>>>(OUT, l_n2_g, l_n2_b, LNF, iBN);
    {
        short* H2 = (short*)(U + (size_t)CB * NPB * 512 * 2);
        for (int b0 = 0; b0 < 8; b0 += CB) {
            int Mc = CB * 12544;
            gemm64<1, 1, 0><<<dim3(8, Mc / 64, 1), 256, 0, stream>>>(
                LNF + (long long)b0 * NPB * 128, 128, 0, WT_LF1, 128, 0, l_f1b,
                H1, 512, 0, nullptr, 0, 0, Mc, 512, 128);
            dwgelu<<<Mc / 4, 256, 0, stream>>>(H1, l_dww, l_dwb, H2);
            gemm64<0, 1, 1><<<dim3(2, Mc / 64, 1), 256, 0, stream>>>(
                H2, 512, 0, WT_LF2, 512, 0, l_f2b,
                OUT + (long long)b0 * NPB * 128, 128, 0,
                OUT + (long long)b0 * NPB * 128, 128, 0, Mc, 128, 512);
        }
    }

    // ---------------- Global attention block ----------------
    ln_kernel<<<25088, 256, 0, stream>>>(OUT, g_n1_g, g_n1_b, LNF, iBN);
    gemm64<1, 1, 0><<<dim3(2, 1568, 1), 256, 0, stream>>>(
        LNF, 128, 0, WT_GQ, 128, 0, g_qb,
        QBUF, 128, 0, nullptr, 0, 0, iBN, 128, 128);
    srgemm<<<dim3(2, 25, 32), 256, 0, stream>>>(LNF, WT_GSR, PART);
    reduceXS<<<784, 256, 0, stream>>>(PART, g_srb, XS);
    ln_kernel<<<392, 256, 0, stream>>>(XS, g_sng, g_snb, XSLN, 1568);
    gemm64<1, 1, 0><<<dim3(4, 25, 1), 256, 0, stream>>>(
        XSLN, 128, 0, WT_GKV, 128, 0, g_kvb,
        KVB, 256, 0, nullptr, 0, 0, 1568, 256, 128);
    gattn<<<dim3(196, 32), 256, 0, stream>>>(QBUF, KVB, ATT);
    gemm64<0, 1, 1><<<dim3(2, 1568, 1), 256, 0, stream>>>(
        ATT, 128, 0, WT_GPW, 128, 0, g_pb,
        OUT, 128, 0, OUT, 128, 0, iBN, 128, 128);

    // ---------------- Global MLP block ----------------
    ln_kernel<<<25088, 256, 0, stream>>>(OUT, g_n2_g, g_n2_b, LNF, iBN);
    {
        short* H2 = (short*)(U + (size_t)CB * NPB * 512 * 2);
        for (int b0 = 0; b0 < 8; b0 += CB) {
            int Mc = CB * 12544;
            gemm64<1, 1, 0><<<dim3(8, Mc / 64, 1), 256, 0, stream>>>(
                LNF + (long long)b0 * NPB * 128, 128, 0, WT_GF1, 128, 0, g_f1b,
                H1, 512, 0, nullptr, 0, 0, Mc, 512, 128);
            dwgelu<<<Mc / 4, 256, 0, stream>>>(H1, g_dww, g_dwb, H2);
            gemm64<0, 1, 1><<<dim3(2, Mc / 64, 1), 256, 0, stream>>>(
                H2, 512, 0, WT_GF2, 512, 0, g_f2b,
                OUT + (long long)b0 * NPB * 128, 128, 0,
                OUT + (long long)b0 * NPB * 128, 128, 0, Mc, 128, 512);
        }
    }
}

// Round 4
// 699.033 us; speedup vs baseline: 2.5778x; 1.1812x over previous
//
#include <hip/hip_runtime.h>
#include <hip/hip_bf16.h>

#define DI __device__ __forceinline__

typedef __attribute__((ext_vector_type(8))) __bf16 bf16x8;
typedef __attribute__((ext_vector_type(8))) short short8;
typedef __attribute__((ext_vector_type(4))) float f32x4;

DI short f2b(float f) {
    union { float f; unsigned u; } v; v.f = f;
    unsigned r = v.u + 0x7FFFu + ((v.u >> 16) & 1u);
    return (short)(r >> 16);
}
DI float b2f(short s) {
    union { unsigned u; float f; } v; v.u = ((unsigned)(unsigned short)s) << 16;
    return v.f;
}

DI void gll16(const short* g, short* l) {
    __builtin_amdgcn_global_load_lds(
        (const __attribute__((address_space(1))) void*)(g),
        (__attribute__((address_space(3))) void*)(l), 16, 0, 0);
}

// fast exact-GELU via A&S 7.1.26 erf poly (|eps|<1.5e-7)
DI float gelu(float a) {
    float z = fabsf(a) * 0.7071067811865475f;
    float t = __builtin_amdgcn_rcpf(fmaf(0.3275911f, z, 1.f));
    float p = t * fmaf(t, fmaf(t, fmaf(t, fmaf(t, 1.061405429f, -1.453152027f),
                                       1.421413741f), -0.284496736f), 0.254829592f);
    float e = __expf(-z * z);
    float er = fmaf(-p, e, 1.f);
    float sg = (a >= 0.f) ? er : -er;
    return 0.5f * a * (1.f + sg);
}

// ---------------------------------------------------------------------------
// 128x128 MFMA bf16 GEMM (m97-structure): C[M][N] = A[M][K] @ Wt[N][K]^T.
// Requires M%128==0, N%128==0, K%32==0. global_load_lds staging, source-side
// XOR swizzle S(r)=(r&3)^((r>>2)&3), linear LDS [128][32].
// ---------------------------------------------------------------------------
template<int OB, int HB, int HR>
__global__ __launch_bounds__(256)
void gemm128(const short* __restrict__ A, int lda,
             const short* __restrict__ Wt, int ldw,
             const float* __restrict__ bias,
             void* __restrict__ Cv, int ldc,
             const float* __restrict__ R, int ldr,
             int K)
{
    __shared__ short As[4096];
    __shared__ short Bs[4096];
    const int m0 = blockIdx.y * 128, n0 = blockIdx.x * 128;
    const int tid = threadIdx.x, lane = tid & 63, w = tid >> 6;
    const int wr = w >> 1, wc = w & 1;
    const int fr = lane & 15, fg = lane >> 4;

    const int i0 = tid, i1 = 256 + tid;
    const int r0 = i0 >> 2, p0 = i0 & 3;
    const int r1 = i1 >> 2, p1 = i1 & 3;
    const int s0 = (r0 & 3) ^ ((r0 >> 2) & 3);
    const int s1 = (r1 & 3) ^ ((r1 >> 2) & 3);
    const short* aptr0 = A + (long long)(m0 + r0) * lda + (p0 ^ s0) * 8;
    const short* aptr1 = A + (long long)(m0 + r1) * lda + (p1 ^ s1) * 8;
    const short* bptr0 = Wt + (long long)(n0 + r0) * ldw + (p0 ^ s0) * 8;
    const short* bptr1 = Wt + (long long)(n0 + r1) * ldw + (p1 ^ s1) * 8;
    short* lA0 = As + w * 512;
    short* lA1 = As + 2048 + w * 512;
    short* lB0 = Bs + w * 512;
    short* lB1 = Bs + 2048 + w * 512;

    const int sf = (fr & 3) ^ ((fr >> 2) & 3);
    const short* pA = As + (wr * 64 + fr) * 32 + (fg ^ sf) * 8;
    const short* pB = Bs + (wc * 64 + fr) * 32 + (fg ^ sf) * 8;

    f32x4 zero = {0.f, 0.f, 0.f, 0.f};
    f32x4 acc[4][4];
    #pragma unroll
    for (int i = 0; i < 4; i++)
        #pragma unroll
        for (int j = 0; j < 4; j++) acc[i][j] = zero;

    for (int k0 = 0; k0 < K; k0 += 32) {
        __syncthreads();
        gll16(aptr0, lA0); gll16(aptr1, lA1);
        gll16(bptr0, lB0); gll16(bptr1, lB1);
        aptr0 += 32; aptr1 += 32; bptr0 += 32; bptr1 += 32;
        __syncthreads();
        bf16x8 af[4], bf[4];
        #pragma unroll
        for (int i = 0; i < 4; i++) af[i] = *(const bf16x8*)(pA + i * 512);
        #pragma unroll
        for (int j = 0; j < 4; j++) bf[j] = *(const bf16x8*)(pB + j * 512);
        #pragma unroll
        for (int i = 0; i < 4; i++)
            #pragma unroll
            for (int j = 0; j < 4; j++)
                acc[i][j] = __builtin_amdgcn_mfma_f32_16x16x32_bf16(af[i], bf[j], acc[i][j], 0, 0, 0);
    }

    #pragma unroll
    for (int ni = 0; ni < 4; ni++) {
        const int cc = n0 + wc * 64 + ni * 16 + fr;
        const float bv = HB ? bias[cc] : 0.f;
        #pragma unroll
        for (int mi = 0; mi < 4; mi++) {
            const int rb = m0 + wr * 64 + mi * 16 + fg * 4;
            #pragma unroll
            for (int v = 0; v < 4; v++) {
                const long long rr = rb + v;
                float val = acc[mi][ni][v] + bv;
                if (HR) val += R[rr * ldr + cc];
                if (OB) ((short*)Cv)[rr * ldc + cc] = f2b(val);
                else    ((float*)Cv)[rr * ldc + cc] = val;
            }
        }
    }
}

// ---------------------------------------------------------------------------
// Generic 64x64 MFMA bf16 GEMM (masked): used for small-M GEMMs (kv).
// ---------------------------------------------------------------------------
template<int OB, int HB, int HR>
__global__ __launch_bounds__(256)
void gemm64(const short* __restrict__ A, int lda, long long sA,
            const short* __restrict__ Wt, int ldw, long long sW,
            const float* __restrict__ bias,
            void* __restrict__ Cv, int ldc, long long sC,
            const float* __restrict__ R, int ldr, long long sR,
            int M, int N, int K)
{
    __shared__ short As[2048];
    __shared__ short Bs[2048];
    const int z = blockIdx.z;
    A  += (long long)z * sA;
    Wt += (long long)z * sW;
    const int m0 = blockIdx.y * 64, n0 = blockIdx.x * 64;
    const int tid = threadIdx.x, lane = tid & 63, wv = tid >> 6;
    const int wr = wv >> 1, wc = wv & 1;
    const int lrow = tid >> 2, lch = tid & 3;
    const int wch = lch ^ (lrow & 3);

    f32x4 zero = {0.f, 0.f, 0.f, 0.f};
    f32x4 acc00 = zero, acc01 = zero, acc10 = zero, acc11 = zero;

    const short* arow = &A[(long long)(m0 + lrow) * lda + lch * 8];
    const short* brow = &Wt[(long long)(n0 + lrow) * ldw + lch * 8];
    short* asw = &As[lrow * 32 + wch * 8];
    short* bsw = &Bs[lrow * 32 + wch * 8];

    const int fr = lane & 15, fg = lane >> 4;
    const int c = ((fg ^ (fr & 3)) * 8);
    const int a0off = (wr * 32 + fr) * 32 + c;
    const int b0off = (wc * 32 + fr) * 32 + c;

    for (int k0 = 0; k0 < K; k0 += 32) {
        uint4 av = *(const uint4*)arow; arow += 32;
        uint4 bv = *(const uint4*)brow; brow += 32;
        __syncthreads();
        *(uint4*)asw = av;
        *(uint4*)bsw = bv;
        __syncthreads();
        bf16x8 a0 = *(const bf16x8*)&As[a0off];
        bf16x8 a1 = *(const bf16x8*)&As[a0off + 512];
        bf16x8 b0 = *(const bf16x8*)&Bs[b0off];
        bf16x8 b1 = *(const bf16x8*)&Bs[b0off + 512];
        acc00 = __builtin_amdgcn_mfma_f32_16x16x32_bf16(a0, b0, acc00, 0, 0, 0);
        acc01 = __builtin_amdgcn_mfma_f32_16x16x32_bf16(a0, b1, acc01, 0, 0, 0);
        acc10 = __builtin_amdgcn_mfma_f32_16x16x32_bf16(a1, b0, acc10, 0, 0, 0);
        acc11 = __builtin_amdgcn_mfma_f32_16x16x32_bf16(a1, b1, acc11, 0, 0, 0);
    }

    const long long cz = (long long)z * sC;
    const int rbase = m0 + wr * 32 + fg * 4;
    const int cbase = n0 + wc * 32 + fr;
    auto emit = [&](f32x4 a, int mi, int ni) {
        int cc = cbase + ni * 16;
        if (cc >= N) return;
        float bv = HB ? bias[cc] : 0.f;
        #pragma unroll
        for (int v = 0; v < 4; v++) {
            int rr = rbase + mi * 16 + v;
            if (rr >= M) continue;
            float val = a[v] + bv;
            if (HR) val += R[(long long)z * sR + (long long)rr * ldr + cc];
            if (OB) ((short*)Cv)[cz + (long long)rr * ldc + cc] = f2b(val);
            else    ((float*)Cv)[cz + (long long)rr * ldc + cc] = val;
        }
    };
    emit(acc00, 0, 0); emit(acc01, 0, 1); emit(acc10, 1, 0); emit(acc11, 1, 1);
}

// ---------------------------------------------------------------------------
// Split-K SR-conv GEMM: gathers 8x8 patches from LNF on the fly.
// ---------------------------------------------------------------------------
__global__ __launch_bounds__(256)
void srgemm(const short* __restrict__ LNF, const short* __restrict__ Wt,
            float* __restrict__ PART)
{
    __shared__ short As[2048];
    __shared__ short Bs[2048];
    const int z = blockIdx.z;
    const int m0 = blockIdx.y * 64, n0 = blockIdx.x * 64;
    const int tid = threadIdx.x, lane = tid & 63, wv = tid >> 6;
    const int wr = wv >> 1, wc = wv & 1;
    const int lrow = tid >> 2, lch = tid & 3;
    const int wch = lch ^ (lrow & 3);

    f32x4 zero = {0.f, 0.f, 0.f, 0.f};
    f32x4 acc00 = zero, acc01 = zero, acc10 = zero, acc11 = zero;

    int row = m0 + lrow;
    int rc = row < 1568 ? row : 1567;
    int b = rc / 196, p = rc % 196;
    int oh = p / 14, ow = p % 14;
    int k0 = z * 256;
    int kh = k0 >> 10, koff = k0 & 1023;
    const short* arow = LNF + ((long long)(b * 12544 + (oh * 8 + kh) * 112 + ow * 8)) * 128
                        + koff + lch * 8;
    const short* brow = Wt + (long long)(n0 + lrow) * 8192 + k0 + lch * 8;
    short* asw = &As[lrow * 32 + wch * 8];
    short* bsw = &Bs[lrow * 32 + wch * 8];

    const int fr = lane & 15, fg = lane >> 4;
    const int c = ((fg ^ (fr & 3)) * 8);
    const int a0off = (wr * 32 + fr) * 32 + c;
    const int b0off = (wc * 32 + fr) * 32 + c;

    for (int kk = 0; kk < 256; kk += 32) {
        uint4 av = *(const uint4*)arow; arow += 32;
        uint4 bv = *(const uint4*)brow; brow += 32;
        __syncthreads();
        *(uint4*)asw = av;
        *(uint4*)bsw = bv;
        __syncthreads();
        bf16x8 a0 = *(const bf16x8*)&As[a0off];
        bf16x8 a1 = *(const bf16x8*)&As[a0off + 512];
        bf16x8 b0 = *(const bf16x8*)&Bs[b0off];
        bf16x8 b1 = *(const bf16x8*)&Bs[b0off + 512];
        acc00 = __builtin_amdgcn_mfma_f32_16x16x32_bf16(a0, b0, acc00, 0, 0, 0);
        acc01 = __builtin_amdgcn_mfma_f32_16x16x32_bf16(a0, b1, acc01, 0, 0, 0);
        acc10 = __builtin_amdgcn_mfma_f32_16x16x32_bf16(a1, b0, acc10, 0, 0, 0);
        acc11 = __builtin_amdgcn_mfma_f32_16x16x32_bf16(a1, b1, acc11, 0, 0, 0);
    }

    const int rbase = m0 + wr * 32 + fg * 4;
    const int cbase = n0 + wc * 32 + fr;
    auto emit = [&](f32x4 a, int mi, int ni) {
        int cc = cbase + ni * 16;
        #pragma unroll
        for (int v = 0; v < 4; v++) {
            int rr = rbase + mi * 16 + v;
            if (rr >= 1568) continue;
            PART[(long long)z * 200704 + (long long)rr * 128 + cc] = a[v];
        }
    };
    emit(acc00, 0, 0); emit(acc01, 0, 1); emit(acc10, 1, 0); emit(acc11, 1, 1);
}

__global__ void reduceXS(const float* __restrict__ PART, const float* __restrict__ bias,
                         float* __restrict__ XS)
{
    int i = blockIdx.x * 256 + threadIdx.x;
    float s = 0.f;
    #pragma unroll
    for (int z = 0; z < 32; z++) s += PART[(long long)z * 200704 + i];
    XS[i] = s + bias[i & 127];
}

// ---------------------------------------------------------------------------
__global__ __launch_bounds__(256)
void ln_kernel(const float* __restrict__ x, const float* __restrict__ g,
               const float* __restrict__ b, short* __restrict__ o, int rows)
{
    int row = blockIdx.x * 4 + (threadIdx.x >> 6);
    if (row >= rows) return;
    int lane = threadIdx.x & 63;
    const float2 v = *(const float2*)&x[(long long)row * 128 + lane * 2];
    float s = v.x + v.y;
    float ss = v.x * v.x + v.y * v.y;
    #pragma unroll
    for (int off = 1; off < 64; off <<= 1) {
        s += __shfl_xor(s, off);
        ss += __shfl_xor(ss, off);
    }
    float mu = s * 0.0078125f;
    float var = ss * 0.0078125f - mu * mu;
    float rs = rsqrtf(var + 1e-5f);
    float2 gg = *(const float2*)&g[lane * 2];
    float2 bb = *(const float2*)&b[lane * 2];
    short2 out;
    out.x = f2b((v.x - mu) * rs * gg.x + bb.x);
    out.y = f2b((v.y - mu) * rs * gg.y + bb.y);
    *(short2*)&o[(long long)row * 128 + lane * 2] = out;
}

__global__ void wtrans(const float* __restrict__ w, short* __restrict__ wt, int K, int N)
{
    long long idx = (long long)blockIdx.x * 256 + threadIdx.x;
    if (idx >= (long long)K * N) return;
    int k = (int)(idx / N), n = (int)(idx % N);
    wt[(long long)n * K + k] = f2b(w[idx]);
}

// ---------------------------------------------------------------------------
// Local windowed attention via MFMA (unchanged from round 2).
// ---------------------------------------------------------------------------
__global__ __launch_bounds__(512)
void lattn(const short* __restrict__ qkv, short* __restrict__ att)
{
    __shared__ short QKs[64 * 264];
    __shared__ short Vt[128 * 72];
    __shared__ short Pl[8 * 16 * 72];
    const int bi = blockIdx.x >> 8;
    const int win = blockIdx.x & 255;
    const int wy = win >> 4, wx = win & 15;
    const long long base = (long long)bi * 12544;
    const int tid = threadIdx.x;

    for (int i = tid; i < 1152; i += 512) {
        uint4 zz = {0, 0, 0, 0};
        *(uint4*)&Vt[i * 8] = zz;
    }
    __syncthreads();

    for (int idx = tid; idx < 2352; idx += 512) {
        int i = idx / 48, ch = idx % 48;
        long long n = base + (wy * 7 + i / 7) * 112 + wx * 7 + i % 7;
        uint4 v = *(const uint4*)&qkv[n * 384 + ch * 8];
        if (ch < 32) {
            *(uint4*)&QKs[i * 264 + ch * 8] = v;
        } else {
            int c0 = (ch - 32) * 8;
            const short* sp = (const short*)&v;
            #pragma unroll
            for (int u = 0; u < 8; u++) {
                int cc = c0 + u;
                Vt[cc * 72 + ((((i >> 3) ^ ((cc >> 3) & 7)) << 3) | (i & 7))] = sp[u];
            }
        }
    }
    __syncthreads();

    const int w = tid >> 6, l = tid & 63;
    const int h = w >> 1, qh = w & 1;
    const int q16 = l & 15, g = l >> 4;
    const float SC = 0.17677669529663689f;
    f32x4 zero = {0.f, 0.f, 0.f, 0.f};

    bf16x8 kf[4];
    #pragma unroll
    for (int kt = 0; kt < 4; kt++)
        kf[kt] = *(const bf16x8*)&QKs[(kt * 16 + q16) * 264 + 128 + h * 32 + g * 8];
    bf16x8 vf[2][2];
    #pragma unroll
    for (int dt = 0; dt < 2; dt++) {
        int cc = h * 32 + dt * 16 + q16;
        #pragma unroll
        for (int s2 = 0; s2 < 2; s2++)
            vf[dt][s2] = *(const bf16x8*)&Vt[cc * 72 + (((s2 * 4 + g) ^ ((cc >> 3) & 7)) << 3)];
    }
    short* pw = &Pl[(w * 16 + q16) * 72];

    for (int qt2 = 0; qt2 < 2; qt2++) {
        int qt = qh * 2 + qt2;
        bf16x8 qf = *(const bf16x8*)&QKs[(qt * 16 + q16) * 264 + h * 32 + g * 8];
        f32x4 s[4];
        #pragma unroll
        for (int kt = 0; kt < 4; kt++)
            s[kt] = __builtin_amdgcn_mfma_f32_16x16x32_bf16(kf[kt], qf, zero, 0, 0, 0);
        float mx = -1e30f;
        #pragma unroll
        for (int kt = 0; kt < 4; kt++) {
            #pragma unroll
            for (int v = 0; v < 4; v++) {
                int k = kt * 16 + g * 4 + v;
                if (k < 49) mx = fmaxf(mx, s[kt][v]);
            }
        }
        mx = fmaxf(mx, __shfl_xor(mx, 16));
        mx = fmaxf(mx, __shfl_xor(mx, 32));
        float sum = 0.f;
        #pragma unroll
        for (int kt = 0; kt < 4; kt++) {
            #pragma unroll
            for (int v = 0; v < 4; v++) {
                int k = kt * 16 + g * 4 + v;
                float p = (k < 49) ? __expf(SC * (s[kt][v] - mx)) : 0.f;
                s[kt][v] = p;
                sum += p;
            }
        }
        sum += __shfl_xor(sum, 16);
        sum += __shfl_xor(sum, 32);
        float inv = 1.f / sum;
        #pragma unroll
        for (int kt = 0; kt < 4; kt++) {
            int lo = ((int)(unsigned short)f2b(s[kt][1] * inv) << 16) | (unsigned short)f2b(s[kt][0] * inv);
            int hi = ((int)(unsigned short)f2b(s[kt][3] * inv) << 16) | (unsigned short)f2b(s[kt][2] * inv);
            int2 pr; pr.x = lo; pr.y = hi;
            *(int2*)&pw[kt * 16 + g * 4] = pr;
        }
        f32x4 o0 = zero, o1 = zero;
        #pragma unroll
        for (int s2 = 0; s2 < 2; s2++) {
            bf16x8 pa = *(const bf16x8*)&pw[s2 * 32 + g * 8];
            o0 = __builtin_amdgcn_mfma_f32_16x16x32_bf16(pa, vf[0][s2], o0, 0, 0, 0);
            o1 = __builtin_amdgcn_mfma_f32_16x16x32_bf16(pa, vf[1][s2], o1, 0, 0, 0);
        }
        #pragma unroll
        for (int v = 0; v < 4; v++) {
            int q = qt * 16 + g * 4 + v;
            if (q < 49) {
                long long n = base + (wy * 7 + q / 7) * 112 + wx * 7 + q % 7;
                att[n * 128 + h * 32 + q16]      = f2b(o0[v]);
                att[n * 128 + h * 32 + 16 + q16] = f2b(o1[v]);
            }
        }
    }
}

// ---------------------------------------------------------------------------
// Fused global attention (unchanged from round 2).
// ---------------------------------------------------------------------------
__global__ __launch_bounds__(256)
void gattn(const short* __restrict__ Q, const short* __restrict__ KVB,
           short* __restrict__ O)
{
    __shared__ short Ks[208 * 40];
    __shared__ short Vt[32 * 232];
    __shared__ short Pl[4 * 16 * 232];
    __shared__ float sums[4][16];
    const int qb = blockIdx.x;
    const int bh = blockIdx.y;
    const int b = bh >> 2, h = bh & 3;
    const int tid = threadIdx.x, w = tid >> 6, l = tid & 63;
    const int q16 = l & 15, g = l >> 4;

    for (int i = tid * 2; i < 208 * 40; i += 512) *(int*)&Ks[i] = 0;
    for (int i = tid * 2; i < 32 * 232; i += 512) *(int*)&Vt[i] = 0;
    __syncthreads();

    const long long kvbase = (long long)(b * 196) * 256 + h * 32;
    for (int idx = tid; idx < 784; idx += 256) {
        int m = idx >> 2, dg = idx & 3;
        uint4 v = *(const uint4*)&KVB[kvbase + (long long)m * 256 + dg * 8];
        *(uint4*)&Ks[m * 40 + dg * 8] = v;
    }
    for (int idx = tid; idx < 6272; idx += 256) {
        int m = idx >> 5, d = idx & 31;
        Vt[d * 232 + m] = KVB[kvbase + (long long)m * 256 + 128 + d];
    }
    const long long qrow = (long long)b * 12544 + qb * 64 + w * 16 + q16;
    bf16x8 qf = *(const bf16x8*)&Q[qrow * 128 + h * 32 + g * 8];
    __syncthreads();

    f32x4 zero = {0.f, 0.f, 0.f, 0.f};
    f32x4 s[13];
    #pragma unroll
    for (int t = 0; t < 13; t++) {
        bf16x8 a = *(const bf16x8*)&Ks[(t * 16 + q16) * 40 + g * 8];
        s[t] = __builtin_amdgcn_mfma_f32_16x16x32_bf16(a, qf, zero, 0, 0, 0);
    }
    const float SC = 0.17677669529663689f;
    float mx = -1e30f;
    #pragma unroll
    for (int t = 0; t < 13; t++) {
        #pragma unroll
        for (int v = 0; v < 4; v++) {
            int k = t * 16 + g * 4 + v;
            if (k < 196) mx = fmaxf(mx, s[t][v]);
        }
    }
    mx = fmaxf(mx, __shfl_xor(mx, 16));
    mx = fmaxf(mx, __shfl_xor(mx, 32));
    float sum = 0.f;
    #pragma unroll
    for (int t = 0; t < 13; t++) {
        #pragma unroll
        for (int v = 0; v < 4; v++) {
            int k = t * 16 + g * 4 + v;
            float pv = (k < 196) ? __expf(SC * (s[t][v] - mx)) : 0.f;
            s[t][v] = pv;
            sum += pv;
        }
    }
    sum += __shfl_xor(sum, 16);
    sum += __shfl_xor(sum, 32);
    if (g == 0) sums[w][q16] = 1.f / sum;

    short* pw = &Pl[(w * 16 + q16) * 232];
    #pragma unroll
    for (int t = 0; t < 13; t++) {
        int lo = ((int)(unsigned short)f2b(s[t][1]) << 16) | (unsigned short)f2b(s[t][0]);
        int hi = ((int)(unsigned short)f2b(s[t][3]) << 16) | (unsigned short)f2b(s[t][2]);
        int2 pr; pr.x = lo; pr.y = hi;
        *(int2*)&pw[t * 16 + g * 4] = pr;
    }
    int2 zz; zz.x = 0; zz.y = 0;
    *(int2*)&pw[208 + g * 4] = zz;
    __syncthreads();

    f32x4 o0 = zero, o1 = zero;
    #pragma unroll
    for (int kc = 0; kc < 7; kc++) {
        bf16x8 pa = *(const bf16x8*)&Pl[(w * 16 + q16) * 232 + kc * 32 + g * 8];
        bf16x8 v0 = *(const bf16x8*)&Vt[q16 * 232 + kc * 32 + g * 8];
        bf16x8 v1 = *(const bf16x8*)&Vt[(16 + q16) * 232 + kc * 32 + g * 8];
        o0 = __builtin_amdgcn_mfma_f32_16x16x32_bf16(pa, v0, o0, 0, 0, 0);
        o1 = __builtin_amdgcn_mfma_f32_16x16x32_bf16(pa, v1, o1, 0, 0, 0);
    }
    float sv[4];
    #pragma unroll
    for (int v = 0; v < 4; v++) sv[v] = sums[w][g * 4 + v];
    const long long obase = ((long long)b * 12544 + qb * 64 + w * 16) * 128 + h * 32;
    #pragma unroll
    for (int v = 0; v < 4; v++) {
        int qv = g * 4 + v;
        O[obase + (long long)qv * 128 + q16]      = f2b(o0[v] * sv[v]);
        O[obase + (long long)qv * 128 + 16 + q16] = f2b(o1[v] * sv[v]);
    }
}

// ---------------------------------------------------------------------------
// Depthwise 3x3 conv + bias + fast exact GELU. Thread = 8 channels x 4-pixel
// vertical run; 6 input rows loaded once and distributed (register rolling).
// ---------------------------------------------------------------------------
__global__ __launch_bounds__(256)
void dwgelu(const short* __restrict__ h1, const float* __restrict__ w,
            const float* __restrict__ bias, short* __restrict__ h2)
{
    const int idx = blockIdx.x * 256 + threadIdx.x;
    const int cb = idx & 63;
    const int run = idx >> 6;
    const int img = run / 3136;
    const int rem = run % 3136;
    const int x = rem / 28;
    const int y0 = (rem % 28) * 4;
    const int c0 = cb << 3;

    float wreg[9][8];
    #pragma unroll
    for (int t = 0; t < 9; t++) {
        float4 lo = *(const float4*)&w[t * 512 + c0];
        float4 hi = *(const float4*)&w[t * 512 + c0 + 4];
        wreg[t][0] = lo.x; wreg[t][1] = lo.y; wreg[t][2] = lo.z; wreg[t][3] = lo.w;
        wreg[t][4] = hi.x; wreg[t][5] = hi.y; wreg[t][6] = hi.z; wreg[t][7] = hi.w;
    }
    float4 blo = *(const float4*)&bias[c0];
    float4 bhi = *(const float4*)&bias[c0 + 4];
    float acc[4][8];
    #pragma unroll
    for (int r = 0; r < 4; r++) {
        acc[r][0] = blo.x; acc[r][1] = blo.y; acc[r][2] = blo.z; acc[r][3] = blo.w;
        acc[r][4] = bhi.x; acc[r][5] = bhi.y; acc[r][6] = bhi.z; acc[r][7] = bhi.w;
    }
    const long long ibase = (long long)img * 12544;

    #pragma unroll
    for (int dy = -1; dy <= 4; dy++) {
        const int yy = y0 + dy;
        const bool rowok = (yy >= 0) && (yy < 112);
        float v[3][8];
        #pragma unroll
        for (int kx = 0; kx < 3; kx++) {
            const int xx = x + kx - 1;
            short8 sv = {0, 0, 0, 0, 0, 0, 0, 0};
            if (rowok && xx >= 0 && xx < 112)
                sv = *(const short8*)&h1[(ibase + yy * 112 + xx) * 512 + c0];
            #pragma unroll
            for (int u = 0; u < 8; u++) v[kx][u] = b2f(sv[u]);
        }
        #pragma unroll
        for (int ky = 0; ky < 3; ky++) {
            const int r = dy + 1 - ky;
            if (r < 0 || r > 3) continue;
            #pragma unroll
            for (int kx = 0; kx < 3; kx++)
                #pragma unroll
                for (int u = 0; u < 8; u++)
                    acc[r][u] = fmaf(v[kx][u], wreg[ky * 3 + kx][u], acc[r][u]);
        }
    }
    #pragma unroll
    for (int r = 0; r < 4; r++) {
        short8 ov;
        #pragma unroll
        for (int u = 0; u < 8; u++) ov[u] = f2b(gelu(acc[r][u]));
        *(short8*)&h2[(ibase + (y0 + r) * 112 + x) * 512 + c0] = ov;
    }
}

// ---------------------------------------------------------------------------
extern "C" void kernel_launch(void* const* d_in, const int* in_sizes, int n_in,
                              void* d_out, int out_size, void* d_ws, size_t ws_size,
                              hipStream_t stream)
{
    (void)in_sizes; (void)n_in; (void)out_size;
    const float* X      = (const float*)d_in[0];
    const float* l_n1_g = (const float*)d_in[1];
    const float* l_n1_b = (const float*)d_in[2];
    const float* l_qkv_w= (const float*)d_in[3];
    const float* l_qkv_b= (const float*)d_in[4];
    const float* l_pw   = (const float*)d_in[5];
    const float* l_pb   = (const float*)d_in[6];
    const float* l_n2_g = (const float*)d_in[7];
    const float* l_n2_b = (const float*)d_in[8];
    const float* l_f1w  = (const float*)d_in[9];
    const float* l_f1b  = (const float*)d_in[10];
    const float* l_dww  = (const float*)d_in[11];
    const float* l_dwb  = (const float*)d_in[12];
    const float* l_f2w  = (const float*)d_in[13];
    const float* l_f2b  = (const float*)d_in[14];
    const float* g_n1_g = (const float*)d_in[15];
    const float* g_n1_b = (const float*)d_in[16];
    const float* g_qw   = (const float*)d_in[17];
    const float* g_qb   = (const float*)d_in[18];
    const float* g_kvw  = (const float*)d_in[19];
    const float* g_kvb  = (const float*)d_in[20];
    const float* g_srw  = (const float*)d_in[21];
    const float* g_srb  = (const float*)d_in[22];
    const float* g_sng  = (const float*)d_in[23];
    const float* g_snb  = (const float*)d_in[24];
    const float* g_pw   = (const float*)d_in[25];
    const float* g_pb   = (const float*)d_in[26];
    const float* g_n2_g = (const float*)d_in[27];
    const float* g_n2_b = (const float*)d_in[28];
    const float* g_f1w  = (const float*)d_in[29];
    const float* g_f1b  = (const float*)d_in[30];
    const float* g_dww  = (const float*)d_in[31];
    const float* g_dwb  = (const float*)d_in[32];
    const float* g_f2w  = (const float*)d_in[33];
    const float* g_f2b  = (const float*)d_in[34];

    const long long NPB = 12544;
    const long long BN  = 100352;
    const int iBN = (int)BN;

    float* OUT = (float*)d_out;
    char* ws = (char*)d_ws;
    size_t off = 0;
    auto alloc = [&](size_t bytes) { size_t o = off; off += (bytes + 255) & ~(size_t)255; return o; };
    short* WT_QKV = (short*)(ws + alloc(384 * 128 * 2));
    short* WT_LPW = (short*)(ws + alloc(128 * 128 * 2));
    short* WT_LF1 = (short*)(ws + alloc(512 * 128 * 2));
    short* WT_LF2 = (short*)(ws + alloc(128 * 512 * 2));
    short* WT_GQ  = (short*)(ws + alloc(128 * 128 * 2));
    short* WT_GKV = (short*)(ws + alloc(256 * 128 * 2));
    short* WT_GSR = (short*)(ws + alloc(128 * 8192 * 2));
    short* WT_GPW = (short*)(ws + alloc(128 * 128 * 2));
    short* WT_GF1 = (short*)(ws + alloc(512 * 128 * 2));
    short* WT_GF2 = (short*)(ws + alloc(128 * 512 * 2));
    short* LNF    = (short*)(ws + alloc((size_t)BN * 128 * 2));
    char*  U      = ws + alloc(0);

    const size_t SZ_H1   = (size_t)BN * 512 * 2;
    const bool big = ws_size >= off + 2 * SZ_H1 + 4096;
    short* QKVB = (short*)(U + 0);
    short* ATT  = (short*)(U + 77070336);
    float* PART = (float*)(U + 0);
    float* XS   = (float*)(U + 25690368);
    short* XSLN = (short*)(U + 26493184);
    short* KVB  = (short*)(U + 26894592);
    short* QBUF = (short*)(U + 27697408);

    wtrans<<<192, 256, 0, stream>>>(l_qkv_w, WT_QKV, 128, 384);
    wtrans<<<64, 256, 0, stream>>>(l_pw, WT_LPW, 128, 128);
    wtrans<<<256, 256, 0, stream>>>(l_f1w, WT_LF1, 128, 512);
    wtrans<<<256, 256, 0, stream>>>(l_f2w, WT_LF2, 512, 128);
    wtrans<<<64, 256, 0, stream>>>(g_qw, WT_GQ, 128, 128);
    wtrans<<<128, 256, 0, stream>>>(g_kvw, WT_GKV, 128, 256);
    wtrans<<<4096, 256, 0, stream>>>(g_srw, WT_GSR, 8192, 128);
    wtrans<<<64, 256, 0, stream>>>(g_pw, WT_GPW, 128, 128);
    wtrans<<<256, 256, 0, stream>>>(g_f1w, WT_GF1, 128, 512);
    wtrans<<<256, 256, 0, stream>>>(g_f2w, WT_GF2, 512, 128);

    const int CB = big ? 8 : 2;
    short* H1 = (short*)(U + 0);

    // ---------------- Local attention block ----------------
    ln_kernel<<<25088, 256, 0, stream>>>(X, l_n1_g, l_n1_b, LNF, iBN);
    gemm128<1, 1, 0><<<dim3(3, 784), 256, 0, stream>>>(
        LNF, 128, WT_QKV, 128, l_qkv_b, QKVB, 384, nullptr, 0, 128);
    lattn<<<2048, 512, 0, stream>>>(QKVB, ATT);
    gemm128<0, 1, 1><<<dim3(1, 784), 256, 0, stream>>>(
        ATT, 128, WT_LPW, 128, l_pb, OUT, 128, X, 128, 128);

    // ---------------- Local MLP block ----------------
    ln_kernel<<<25088, 256, 0, stream>>>(OUT, l_n2_g, l_n2_b, LNF, iBN);
    {
        short* H2 = (short*)(U + (size_t)CB * NPB * 512 * 2);
        for (int b0 = 0; b0 < 8; b0 += CB) {
            int Mc = CB * 12544;
            gemm128<1, 1, 0><<<dim3(4, Mc / 128), 256, 0, stream>>>(
                LNF + (long long)b0 * NPB * 128, 128, WT_LF1, 128, l_f1b,
                H1, 512, nullptr, 0, 128);
            dwgelu<<<CB * 784, 256, 0, stream>>>(H1, l_dww, l_dwb, H2);
            gemm128<0, 1, 1><<<dim3(1, Mc / 128), 256, 0, stream>>>(
                H2, 512, WT_LF2, 512, l_f2b,
                OUT + (long long)b0 * NPB * 128, 128,
                OUT + (long long)b0 * NPB * 128, 128, 512);
        }
    }

    // ---------------- Global attention block ----------------
    ln_kernel<<<25088, 256, 0, stream>>>(OUT, g_n1_g, g_n1_b, LNF, iBN);
    gemm128<1, 1, 0><<<dim3(1, 784), 256, 0, stream>>>(
        LNF, 128, WT_GQ, 128, g_qb, QBUF, 128, nullptr, 0, 128);
    srgemm<<<dim3(2, 25, 32), 256, 0, stream>>>(LNF, WT_GSR, PART);
    reduceXS<<<784, 256, 0, stream>>>(PART, g_srb, XS);
    ln_kernel<<<392, 256, 0, stream>>>(XS, g_sng, g_snb, XSLN, 1568);
    gemm64<1, 1, 0><<<dim3(4, 25, 1), 256, 0, stream>>>(
        XSLN, 128, 0, WT_GKV, 128, 0, g_kvb,
        KVB, 256, 0, nullptr, 0, 0, 1568, 256, 128);
    gattn<<<dim3(196, 32), 256, 0, stream>>>(QBUF, KVB, ATT);
    gemm128<0, 1, 1><<<dim3(1, 784), 256, 0, stream>>>(
        ATT, 128, WT_GPW, 128, g_pb, OUT, 128, OUT, 128, 128);

    // ---------------- Global MLP block ----------------
    ln_kernel<<<25088, 256, 0, stream>>>(OUT, g_n2_g, g_n2_b, LNF, iBN);
    {
        short* H2 = (short*)(U + (size_t)CB * NPB * 512 * 2);
        for (int b0 = 0; b0 < 8; b0 += CB) {
            int Mc = CB * 12544;
            gemm128<1, 1, 0><<<dim3(4, Mc / 128), 256, 0, stream>>>(
                LNF + (long long)b0 * NPB * 128, 128, WT_GF1, 128, g_f1b,
                H1, 512, nullptr, 0, 128);
            dwgelu<<<CB * 784, 256, 0, stream>>>(H1, g_dww, g_dwb, H2);
            gemm128<0, 1, 1><<<dim3(1, Mc / 128), 256, 0, stream>>>(
                H2, 512, WT_GF2, 512, g_f2b,
                OUT + (long long)b0 * NPB * 128, 128,
                OUT + (long long)b0 * NPB * 128, 128, 512);
        }
    }
}